// Round 7
// baseline (1549.132 us; speedup 1.0000x reference)
//
#include <hip/hip_runtime.h>
#include <stdint.h>

typedef unsigned short u16;
typedef short short8 __attribute__((ext_vector_type(8)));
typedef float f32x4 __attribute__((ext_vector_type(4)));
typedef __bf16 bf16x8 __attribute__((ext_vector_type(8)));

#define DEV static __device__ __forceinline__

DEV float bf2f(u16 h) {
  union { unsigned u; float f; } v; v.u = ((unsigned)h) << 16; return v.f;
}
DEV u16 f2bf(float f) {
  union { float f; unsigned u; } v; v.f = f;
  return (u16)((v.u + 0x7fffu + ((v.u >> 16) & 1u)) >> 16);  // RNE
}

// ---------------------------------------------------------------------------
// Transpose to bf16 [C, Kpad]: dst[c][r] = cvt(src[r][c]) for r<R, else 0.
// Turns every GEMM B-operand into the vectorized [N,K] short8 path.
// grid: (ceil(Kpad/64), ceil(C/64)), block 256. Kpad, ldd multiples of 8.
// ---------------------------------------------------------------------------
template<bool F32>
__global__ void tr_k(const void* __restrict__ src, int R, int C, int lds,
                     u16* __restrict__ dst, int ldd, int Kpad)
{
  __shared__ u16 tile[64][72];
  const int t = threadIdx.x;
  const int r0 = blockIdx.x << 6, c0 = blockIdx.y << 6;
  const int sr = t >> 2, sc = (t & 3) << 4;
  #pragma unroll
  for (int j = 0; j < 16; ++j) {
    const int r = r0 + sr, c = c0 + sc + j;
    u16 v = 0;
    if (r < R && c < C)
      v = F32 ? f2bf(((const float*)src)[(size_t)r * lds + c])
              : ((const u16*)src)[(size_t)r * lds + c];
    tile[sr][sc + j] = v;
  }
  __syncthreads();
  const int dc = t >> 2, dr = (t & 3) << 4;
  const int gc = c0 + dc;
  if (gc < C) {
    #pragma unroll
    for (int h = 0; h < 2; ++h) {
      const int gr = r0 + dr + (h << 3);
      if (gr < Kpad) {                 // gr, Kpad both mult of 8
        short8 o;
        #pragma unroll
        for (int j = 0; j < 8; ++j) o[j] = (short)tile[dr + (h << 3) + j][dc];
        *(short8*)&dst[(size_t)gc * ldd + gr] = o;
      }
    }
  }
}

// ---------------------------------------------------------------------------
// MFMA GEMM: C[M,N] = act(A @ B + bias), f32 accumulate, software-pipelined
// staging. A row-major [M,K] f32/bf16; B: LB=0 [K,N] (legacy) / LB=1 [N,K].
// MODE: 0 plain,1 +bias,2 lrelu,3 sigmoid. OUTBF: bf16 C.
// ---------------------------------------------------------------------------
template<int MODE, bool AF32, bool BF32, int LB, bool OUTBF>
__global__ __launch_bounds__(256, 2) void mg(
    const void* __restrict__ Av, int lda,
    const void* __restrict__ Bv, int ldb,
    void* __restrict__ Cv, int ldc,
    int M, int N, int K, int Kreal,
    const float* __restrict__ bias)
{
  __shared__ u16 As[128 * 40];
  __shared__ u16 Bs[128 * 40];
  const int t = threadIdx.x;
  const int w = t >> 6, l = t & 63;
  const int l15 = l & 15, lhi = l >> 4;
  const int bm = blockIdx.y << 7, bn = blockIdx.x << 7;
  const int wm = (w >> 1) << 6, wn = (w & 1) << 6;
  const int srow = t >> 2, scol = (t & 3) << 3;
  const int bcol = t & 127, bkh = (t >> 7) << 4;

  f32x4 acc[4][4] = {};
  short8 pa[2], pb[2];

  auto LDA_ = [&](int kt) {
    #pragma unroll
    for (int c = 0; c < 2; ++c) {
      const int gc = kt + scol;
      short8 v = {};
      const int ga = bm + srow + (c << 6);
      if ((gc + 8 <= K) && ga < M) {
        if (AF32) {
          const float* p = (const float*)Av + (size_t)ga * lda + gc;
          #pragma unroll
          for (int j = 0; j < 8; ++j) v[j] = (short)f2bf(p[j]);
        } else {
          v = *(const short8*)((const u16*)Av + (size_t)ga * lda + gc);
        }
      }
      pa[c] = v;
    }
  };
  auto LDB_ = [&](int kt) {
    if (LB == 1) {
      #pragma unroll
      for (int c = 0; c < 2; ++c) {
        const int gc = kt + scol;
        short8 v = {};
        const int gn = bn + srow + (c << 6);
        if ((gc + 8 <= K) && gn < N) {
          if (BF32) {
            const float* p = (const float*)Bv + (size_t)gn * ldb + gc;
            #pragma unroll
            for (int j = 0; j < 8; ++j) v[j] = (short)f2bf(p[j]);
          } else {
            v = *(const short8*)((const u16*)Bv + (size_t)gn * ldb + gc);
          }
        }
        pb[c] = v;
      }
    } else {
      #pragma unroll
      for (int h = 0; h < 2; ++h) {
        const int k0 = bkh + (h << 3);
        short8 v = {};
        const int gn = bn + bcol;
        if (gn < N) {
          #pragma unroll
          for (int j = 0; j < 8; ++j) {
            const int gk = kt + k0 + j;
            if (gk < Kreal) {
              if (BF32) v[j] = (short)f2bf(((const float*)Bv)[(size_t)gk * ldb + gn]);
              else      v[j] = (short)((const u16*)Bv)[(size_t)gk * ldb + gn];
            }
          }
        }
        pb[h] = v;
      }
    }
  };

  LDA_(0); LDB_(0);
  for (int kt = 0; kt < K; kt += 32) {
    #pragma unroll
    for (int c = 0; c < 2; ++c)
      *(short8*)&As[(srow + (c << 6)) * 40 + scol] = pa[c];
    if (LB == 1) {
      #pragma unroll
      for (int c = 0; c < 2; ++c)
        *(short8*)&Bs[(srow + (c << 6)) * 40 + scol] = pb[c];
    } else {
      #pragma unroll
      for (int h = 0; h < 2; ++h)
        *(short8*)&Bs[bcol * 40 + bkh + (h << 3)] = pb[h];
    }
    __syncthreads();
    if (kt + 32 < K) { LDA_(kt + 32); LDB_(kt + 32); }
    short8 af[4], bfr[4];
    #pragma unroll
    for (int m = 0; m < 4; ++m)
      af[m] = *(const short8*)&As[(wm + (m << 4) + l15) * 40 + (lhi << 3)];
    #pragma unroll
    for (int n = 0; n < 4; ++n)
      bfr[n] = *(const short8*)&Bs[(wn + (n << 4) + l15) * 40 + (lhi << 3)];
    #pragma unroll
    for (int m = 0; m < 4; ++m) {
      #pragma unroll
      for (int n = 0; n < 4; ++n)
        acc[m][n] = __builtin_amdgcn_mfma_f32_16x16x32_bf16(
            __builtin_bit_cast(bf16x8, af[m]),
            __builtin_bit_cast(bf16x8, bfr[n]), acc[m][n], 0, 0, 0);
    }
    __syncthreads();
  }

  #pragma unroll
  for (int m = 0; m < 4; ++m) {
    #pragma unroll
    for (int n = 0; n < 4; ++n) {
      #pragma unroll
      for (int r = 0; r < 4; ++r) {
        const int row = bm + wm + (m << 4) + (lhi << 2) + r;
        const int col = bn + wn + (n << 4) + l15;
        if (row < M && col < N) {
          const float v0 = acc[m][n][r];
          float o;
          if (MODE == 0) o = v0;
          else if (MODE == 1) o = v0 + bias[col];
          else if (MODE == 2) { const float s = v0 + bias[col]; o = (s > 0.f) ? s : 0.2f * s; }
          else o = 1.f / (1.f + __expf(-v0));
          if (OUTBF) ((u16*)Cv)[(size_t)row * ldc + col] = f2bf(o);
          else       ((float*)Cv)[(size_t)row * ldc + col] = o;
        }
      }
    }
  }
}

// ---------------------------------------------------------------------------
// Split-K MFMA GEMM (narrow N<=128). B is ALWAYS bf16 B^T [N,K] (vectorized
// short8 loads — the scalar column-gather path is gone).
// Grid (1, M/128, KS); partials P[z][row][0..PN).
// ---------------------------------------------------------------------------
template<bool AF32>
__global__ __launch_bounds__(256, 2) void mgs(
    const void* __restrict__ Av, int lda,
    const u16* __restrict__ Bt, int ldb,
    float* __restrict__ P,
    int M, int N, int K, int KSZ, int PN)
{
  __shared__ u16 As[128 * 40];
  __shared__ u16 Bs[128 * 40];
  const int t = threadIdx.x;
  const int w = t >> 6, l = t & 63;
  const int l15 = l & 15, lhi = l >> 4;
  const int bm = blockIdx.y << 7;
  const int wm = (w >> 1) << 6, wn = (w & 1) << 6;
  const int srow = t >> 2, scol = (t & 3) << 3;
  const int kbeg = blockIdx.z * KSZ;
  const int kend = min(K, kbeg + KSZ);

  f32x4 acc[4][4] = {};
  short8 pa[2], pb[2];

  auto LDA_ = [&](int kt) {
    #pragma unroll
    for (int c = 0; c < 2; ++c) {
      const int gc = kt + scol;
      short8 v = {};
      const int ga = bm + srow + (c << 6);
      if ((gc + 8 <= K) && ga < M) {
        if (AF32) {
          const float* p = (const float*)Av + (size_t)ga * lda + gc;
          #pragma unroll
          for (int j = 0; j < 8; ++j) v[j] = (short)f2bf(p[j]);
        } else {
          v = *(const short8*)((const u16*)Av + (size_t)ga * lda + gc);
        }
      }
      pa[c] = v;
    }
  };
  auto LDB_ = [&](int kt) {
    #pragma unroll
    for (int c = 0; c < 2; ++c) {
      const int gc = kt + scol;
      short8 v = {};
      const int gn = srow + (c << 6);
      if ((gc + 8 <= K) && gn < N)
        v = *(const short8*)(Bt + (size_t)gn * ldb + gc);
      pb[c] = v;
    }
  };

  LDA_(kbeg); LDB_(kbeg);
  for (int kt = kbeg; kt < kend; kt += 32) {
    #pragma unroll
    for (int c = 0; c < 2; ++c)
      *(short8*)&As[(srow + (c << 6)) * 40 + scol] = pa[c];
    #pragma unroll
    for (int c = 0; c < 2; ++c)
      *(short8*)&Bs[(srow + (c << 6)) * 40 + scol] = pb[c];
    __syncthreads();
    if (kt + 32 < kend) { LDA_(kt + 32); LDB_(kt + 32); }
    short8 af[4], bfr[4];
    #pragma unroll
    for (int m = 0; m < 4; ++m)
      af[m] = *(const short8*)&As[(wm + (m << 4) + l15) * 40 + (lhi << 3)];
    #pragma unroll
    for (int n = 0; n < 4; ++n)
      bfr[n] = *(const short8*)&Bs[(wn + (n << 4) + l15) * 40 + (lhi << 3)];
    #pragma unroll
    for (int m = 0; m < 4; ++m) {
      #pragma unroll
      for (int n = 0; n < 4; ++n)
        acc[m][n] = __builtin_amdgcn_mfma_f32_16x16x32_bf16(
            __builtin_bit_cast(bf16x8, af[m]),
            __builtin_bit_cast(bf16x8, bfr[n]), acc[m][n], 0, 0, 0);
    }
    __syncthreads();
  }

  float* Pz = P + (size_t)blockIdx.z * M * PN;
  #pragma unroll
  for (int m = 0; m < 4; ++m) {
    #pragma unroll
    for (int n = 0; n < 4; ++n) {
      const int col = wn + (n << 4) + l15;
      if (col < PN) {
        #pragma unroll
        for (int r = 0; r < 4; ++r) {
          const int row = bm + wm + (m << 4) + (lhi << 2) + r;
          Pz[(size_t)row * PN + col] = acc[m][n][r];
        }
      }
    }
  }
}

template<int MODE, bool OUTBF>
__global__ void redk(const float* __restrict__ P, int KS, int PN,
                     void* __restrict__ Cv, int M, int N,
                     const float* __restrict__ bias)
{
  const int i = blockIdx.x * 256 + threadIdx.x;
  if (i >= M * N) return;
  const int row = i / N, col = i - row * N;
  float s = 0.f;
  for (int z = 0; z < KS; ++z) s += P[((size_t)z * M + row) * PN + col];
  float o;
  if (MODE == 0) o = s;
  else if (MODE == 1) o = s + bias[col];
  else { const float b = s + bias[col]; o = (b > 0.f) ? b : 0.2f * b; }
  if (OUTBF) ((u16*)Cv)[i] = f2bf(o);
  else       ((float*)Cv)[i] = o;
}

// ---------------------------------------------------------------------------
// Fused symmetric dual gram (r4 K-loop, identity block mapping — r6's XCD
// band swizzle REVERTED: with the triangular early-exit grid it put ~484
// active blocks on XCD0 vs ~36 on XCD7 (occupancy 15->10.6, FETCH 197->463MB).
// This round's single change: __launch_bounds__ 2 -> 4 blocks/CU (VGPR 96
// <= 128 cap, LDS 4x20KB <= 160KB) to fill the ~4x latency gap the r4 cycle
// model exposed (1525 cy/block-step vs ~375 LDS + ~258 MFMA busy).
// ---------------------------------------------------------------------------
template<bool TEST>
__global__ __launch_bounds__(256, 4) void gram2(
    const u16* __restrict__ Z1, int ld1, int K1,
    const u16* __restrict__ Z2, int ld2, int K2,
    float* __restrict__ C, int ldc, int M)
{
  __shared__ union SM {
    u16 stage[2][128 * 40];
    float tb[32][132];
  } sm;
  const int bx = blockIdx.x, by = blockIdx.y;
  if (bx < by) return;
  u16* As = sm.stage[0];
  u16* Bs = sm.stage[1];
  const int t = threadIdx.x;
  const int w = t >> 6, l = t & 63;
  const int l15 = l & 15, lhi = l >> 4;
  const int bm = by << 7, bn = bx << 7;
  const int wm = (w >> 1) << 6, wn = (w & 1) << 6;
  const int srow = t >> 2, scol = (t & 3) << 3;

  f32x4 acc1[4][4] = {};
  f32x4 acc2[4][4] = {};
  short8 va0, va1, vb0, vb1;

  auto LOD = [&](const u16* Z, int ld, int KK, int kt) {
    short8 a0 = {}, a1 = {}, b0 = {}, b1 = {};
    const int gc = kt + scol;
    if (gc + 8 <= KK) {
      a0 = *(const short8*)(Z + (size_t)(bm + srow) * ld + gc);
      a1 = *(const short8*)(Z + (size_t)(bm + srow + 64) * ld + gc);
      b0 = *(const short8*)(Z + (size_t)(bn + srow) * ld + gc);
      b1 = *(const short8*)(Z + (size_t)(bn + srow + 64) * ld + gc);
    }
    va0 = a0; va1 = a1; vb0 = b0; vb1 = b1;
  };
  auto STORE = [&]() {
    *(short8*)&As[srow * 40 + scol] = va0;
    *(short8*)&As[(srow + 64) * 40 + scol] = va1;
    *(short8*)&Bs[srow * 40 + scol] = vb0;
    *(short8*)&Bs[(srow + 64) * 40 + scol] = vb1;
  };
  auto FMM = [&](f32x4 (&ACC)[4][4]) {
    short8 af[4], bfr[4];
    #pragma unroll
    for (int m = 0; m < 4; ++m)
      af[m] = *(const short8*)&As[(wm + (m << 4) + l15) * 40 + (lhi << 3)];
    #pragma unroll
    for (int n = 0; n < 4; ++n)
      bfr[n] = *(const short8*)&Bs[(wn + (n << 4) + l15) * 40 + (lhi << 3)];
    #pragma unroll
    for (int m = 0; m < 4; ++m) {
      #pragma unroll
      for (int n = 0; n < 4; ++n)
        ACC[m][n] = __builtin_amdgcn_mfma_f32_16x16x32_bf16(
            __builtin_bit_cast(bf16x8, af[m]),
            __builtin_bit_cast(bf16x8, bfr[n]), ACC[m][n], 0, 0, 0);
    }
  };

  LOD(Z1, ld1, K1, 0);
  for (int kt = 0; kt < K1; kt += 32) {
    STORE();
    __syncthreads();
    if (kt + 32 < K1) LOD(Z1, ld1, K1, kt + 32);
    else LOD(Z2, ld2, K2, 0);
    FMM(acc1);
    __syncthreads();
  }
  for (int kt = 0; kt < K2; kt += 32) {
    STORE();
    __syncthreads();
    if (kt + 32 < K2) LOD(Z2, ld2, K2, kt + 32);
    FMM(acc2);
    __syncthreads();
  }

  auto cval = [&](int m, int n, int r) -> float {
    const float a1 = acc1[m][n][r], a2 = acc2[m][n][r];
    if (TEST) return a1 + a2;
    return 1.f / (1.f + __expf(-a1)) + 1.f / (1.f + __expf(-a2));
  };

  #pragma unroll
  for (int m = 0; m < 4; ++m) {
    #pragma unroll
    for (int n = 0; n < 4; ++n) {
      #pragma unroll
      for (int r = 0; r < 4; ++r) {
        const int row = bm + wm + (m << 4) + (lhi << 2) + r;
        const int col = bn + wn + (n << 4) + l15;
        C[(size_t)row * ldc + col] = cval(m, n, r);
      }
    }
  }

  if (bx != by) {
    #pragma unroll
    for (int p = 0; p < 4; ++p) {
      __syncthreads();
      if (wn == ((p & 2) << 5)) {
        #pragma unroll
        for (int n2 = 0; n2 < 2; ++n2) {
          const int n = ((p & 1) << 1) + n2;
          #pragma unroll
          for (int m = 0; m < 4; ++m)
            #pragma unroll
            for (int r = 0; r < 4; ++r)
              sm.tb[(n2 << 4) + l15][wm + (m << 4) + (lhi << 2) + r] = cval(m, n, r);
        }
      }
      __syncthreads();
      #pragma unroll
      for (int i = 0; i < 16; ++i) {
        const int e = t + (i << 8);
        const int rr = e >> 7, cc = e & 127;
        C[(size_t)(bn + (p << 5) + rr) * ldc + bm + cc] = sm.tb[rr][cc];
      }
    }
  }
}

// --------------------------- small kernels ---------------------------------
__global__ void zi_k(const float* __restrict__ a, const float* __restrict__ zae,
                     const float* __restrict__ zsg, u16* __restrict__ zi)
{
  const int i = blockIdx.x * 256 + threadIdx.x;
  if (i < 163840) {
    const float av = a[i];
    zi[i] = f2bf(av * zae[i] + (1.f - av) * zsg[i]);
  }
}

__global__ void copyf_k(const float* __restrict__ src, float* __restrict__ dst, int n)
{
  const int i = blockIdx.x * 256 + threadIdx.x;
  if (i < n) dst[i] = src[i];
}

__global__ void f2bf4_k(const float* __restrict__ s, u16* __restrict__ d, long n4)
{
  long i = (long)blockIdx.x * 256 + threadIdx.x;
  const long stride = (long)gridDim.x * 256;
  for (; i < n4; i += stride) {
    const float4 v = ((const float4*)s)[i];
    union { u16 h[4]; unsigned long long u; } o;
    o.h[0] = f2bf(v.x); o.h[1] = f2bf(v.y); o.h[2] = f2bf(v.z); o.h[3] = f2bf(v.w);
    ((unsigned long long*)d)[i] = o.u;
  }
}

// 8192 x 2000 f32 -> 8192 x 2016 bf16, zero pad cols [2000,2016).
__global__ void padzhb_k(const float* __restrict__ s, u16* __restrict__ d)
{
  const int row = blockIdx.x;
  for (int g = threadIdx.x; g < 504; g += 256) {
    const int c4 = g << 2;
    union { u16 h[4]; unsigned long long u; } o;
    if (c4 < 2000) {
      const float4 v = *(const float4*)(s + (size_t)row * 2000 + c4);
      o.h[0] = f2bf(v.x); o.h[1] = f2bf(v.y); o.h[2] = f2bf(v.z); o.h[3] = f2bf(v.w);
    } else {
      o.u = 0ULL;
    }
    *(unsigned long long*)(d + (size_t)row * 2016 + c4) = o.u;
  }
}

__global__ void padbf_k(const float* __restrict__ s, u16* __restrict__ d)
{
  const int i = blockIdx.x * 256 + threadIdx.x;
  const int row = i >> 5, col = i & 31;
  d[i] = (col < 20) ? f2bf(s[row * 20 + col]) : (u16)0;
}

__global__ __launch_bounds__(256) void attn_f(const float* __restrict__ zl,
                                              const float* __restrict__ gammap,
                                              u16* __restrict__ ztp,
                                              float* __restrict__ ztout)
{
  __shared__ float tile[256 * 20];
  const int t = threadIdx.x;
  const int sub = t & 31;
  const int row = blockIdx.x * 8 + (t >> 5);
  float qv[20];
  #pragma unroll
  for (int k = 0; k < 20; ++k) qv[k] = zl[(size_t)row * 20 + k];
  float m = -1e30f, ssum = 0.f;
  float acc[20] = {};
  for (int j0 = 0; j0 < 8192; j0 += 256) {
    #pragma unroll
    for (int k = 0; k < 20; ++k) tile[t * 20 + k] = zl[(size_t)(j0 + t) * 20 + k];
    __syncthreads();
    for (int jj = 0; jj < 8; ++jj) {
      const int jl = (jj << 5) + sub;
      float s = 0.f;
      #pragma unroll
      for (int k = 0; k < 20; ++k) s += qv[k] * tile[jl * 20 + k];
      if (s > m) {
        const float sc = __expf(m - s);
        ssum *= sc;
        #pragma unroll
        for (int k = 0; k < 20; ++k) acc[k] *= sc;
        m = s;
      }
      const float p = __expf(s - m);
      ssum += p;
      #pragma unroll
      for (int k = 0; k < 20; ++k) acc[k] += p * tile[jl * 20 + k];
    }
    __syncthreads();
  }
  #pragma unroll
  for (int off = 16; off >= 1; off >>= 1) {
    const float mo = __shfl_xor(m, off, 32);
    const float so = __shfl_xor(ssum, off, 32);
    const float nm = fmaxf(m, mo);
    const float e1 = __expf(m - nm), e2 = __expf(mo - nm);
    ssum = ssum * e1 + so * e2;
    #pragma unroll
    for (int k = 0; k < 20; ++k) {
      const float ao = __shfl_xor(acc[k], off, 32);
      acc[k] = acc[k] * e1 + ao * e2;
    }
    m = nm;
  }
  if (sub == 0) {
    const float g = gammap[0];
    #pragma unroll
    for (int k = 0; k < 20; ++k) {
      const float v = g * (acc[k] / ssum) + qv[k];
      ztout[(size_t)row * 20 + k] = v;
      ztp[(size_t)row * 32 + k] = f2bf(v);
    }
    #pragma unroll
    for (int k = 20; k < 32; ++k) ztp[(size_t)row * 32 + k] = 0;
  }
}

template<bool BFIN>
__global__ void softassign_k(const void* __restrict__ zp, int stride,
                             const float* __restrict__ cl, float* __restrict__ outq)
{
  const int i = blockIdx.x * 256 + threadIdx.x;
  float zv[20];
  #pragma unroll
  for (int k = 0; k < 20; ++k)
    zv[k] = BFIN ? bf2f(((const u16*)zp)[(size_t)i * stride + k])
                 : ((const float*)zp)[(size_t)i * stride + k];
  float qv[10], s = 0.f;
  #pragma unroll
  for (int j = 0; j < 10; ++j) {
    float d2 = 0.f;
    #pragma unroll
    for (int k = 0; k < 20; ++k) { const float d = zv[k] - cl[j * 20 + k]; d2 += d * d; }
    qv[j] = 1.f / (1.f + d2);
    s += qv[j];
  }
  const float inv = 1.f / s;
  #pragma unroll
  for (int j = 0; j < 10; ++j) outq[(size_t)i * 10 + j] = qv[j] * inv;
}

// --------------------------- self-test -------------------------------------
DEV float stA(int i, int k) { return (float)(((i * 5 + k * 7) % 3) - 1); }
DEV float stB(int j, int k) { return (float)(((j * 11 + k * 13) % 5) - 2); }

__global__ void st_setup(u16* At, float* Atf, u16* Bnk, float* Bknf, u16* Bknb, int* fl)
{
  const int idx = blockIdx.x * 256 + threadIdx.x;
  { const int i = idx >> 6, k = idx & 63;
    At[idx] = f2bf(stA(i, k)); Atf[idx] = stA(i, k);
    Bnk[idx] = f2bf(stB(i, k)); }
  { const int k = idx >> 7, j = idx & 127;
    Bknf[idx] = stB(j, k); Bknb[idx] = f2bf(stB(j, k)); }
  if (idx == 0) *fl = 0;
}

__global__ void st_check(const float* C, int bit, int* fl)
{
  const int i = blockIdx.x, j = threadIdx.x;
  float ref = 0.f;
  for (int k = 0; k < 64; ++k) ref += stA(i, k) * stB(j, k);
  if (C[i * 128 + j] != ref) atomicOr(fl, bit);
}

__global__ void st2_setup(u16* Z1, u16* Z2)
{
  const int idx = blockIdx.x * 256 + threadIdx.x;
  if (idx < 8192)  { const int i = idx >> 5, k = idx & 31; Z1[idx] = f2bf(stA(i, k)); }
  if (idx < 16384) { const int i = idx >> 6, k = idx & 63; Z2[idx] = f2bf(stB(i, k)); }
}

__global__ void st2_check(const float* C, int* fl)
{
  const int i = blockIdx.x, j = threadIdx.x;
  float ref = 0.f;
  for (int k = 0; k < 32; ++k) ref += stA(i, k) * stA(j, k);
  for (int k = 0; k < 64; ++k) ref += stB(i, k) * stB(j, k);
  if (C[i * 256 + j] != ref) atomicOr(fl, 16);
}

__global__ void st_probe(float* out0, const int* fl)
{
  if (threadIdx.x == 0 && blockIdx.x == 0 && *fl) *out0 = 4096.f + (float)(*fl);
}

// ---------------------------------------------------------------------------
extern "C" void kernel_launch(void* const* d_in, const int* in_sizes, int n_in,
                              void* d_out, int out_size, void* d_ws, size_t ws_size,
                              hipStream_t stream)
{
  (void)in_sizes; (void)n_in; (void)out_size;
  const float* x     = (const float*)d_in[0];
  const float* adj   = (const float*)d_in[1];
  const float* a     = (const float*)d_in[2];
  const float* cl    = (const float*)d_in[3];
  const float* gamma = (const float*)d_in[4];
  const float* We1 = (const float*)d_in[5];  const float* be1 = (const float*)d_in[6];
  const float* We2 = (const float*)d_in[7];  const float* be2 = (const float*)d_in[8];
  const float* We3 = (const float*)d_in[9];  const float* be3 = (const float*)d_in[10];
  const float* Wz  = (const float*)d_in[11]; const float* bz  = (const float*)d_in[12];
  const float* Wd1 = (const float*)d_in[13]; const float* bd1 = (const float*)d_in[14];
  const float* Wd2 = (const float*)d_in[15]; const float* bd2 = (const float*)d_in[16];
  const float* Wd3 = (const float*)d_in[17]; const float* bd3 = (const float*)d_in[18];
  const float* Wx  = (const float*)d_in[19]; const float* bx  = (const float*)d_in[20];
  const float* Wg1 = (const float*)d_in[21];
  const float* Wg2 = (const float*)d_in[22];
  const float* Wg3 = (const float*)d_in[23];
  const float* Wg4 = (const float*)d_in[24];
  const float* Wg5 = (const float*)d_in[25];
  const float* Wg6 = (const float*)d_in[26];
  float* out = (float*)d_out;

  const size_t OFF_XHAT = 0;
  const size_t OFF_ZHAT = 16384000;
  const size_t OFF_ADJ  = 32768000;
  const size_t OFF_ZAE  = 99876864;
  const size_t OFF_ZSG  = 100040704;
  const size_t OFF_Q    = 100204544;
  const size_t OFF_Q1   = 100286464;
  const size_t OFF_Q2   = 100368384;
  const size_t OFF_ZT   = 100450304;

  char* cur = (char*)d_ws;
  auto ab = [&](size_t bytes) {
    char* p = cur;
    cur += ((bytes + 255) & ~(size_t)255);
    return p;
  };
  u16*  h1   = (u16*)ab(8192 * 128 * 2);
  u16*  h2   = (u16*)ab(8192 * 256 * 2);
  u16*  h3   = (u16*)ab(8192 * 512 * 2);
  u16*  tA   = (u16*)ab(8192 * 128 * 2);
  u16*  tB   = (u16*)ab(8192 * 128 * 2);
  u16*  tC   = (u16*)ab(8192 * 256 * 2);
  u16*  av   = (u16*)ab(8192 * 128 * 2);
  u16*  t3   = (u16*)ab(8192 * 20 * 2);
  float* zae = (float*)ab(8192 * 20 * 4);
  float* zsg = (float*)ab(8192 * 20 * 4);
  u16*  zsgb = (u16*)ab(8192 * 32 * 2);
  u16*  zib  = (u16*)ab(8192 * 20 * 2);
  float* zl  = (float*)ab(8192 * 20 * 4);
  u16*  ztp  = (u16*)ab(8192 * 32 * 2);
  u16*  aztp = (u16*)ab(8192 * 32 * 2);
  float* W45 = (float*)ab(20 * 128 * 4);
  u16*  zhb  = (u16*)ab((size_t)8192 * 2016 * 2);
  u16*  xb   = (u16*)ab((size_t)8192 * 2000 * 2);
  // transposed-B operands (bf16 [N,K])
  u16*  trB  = (u16*)ab((size_t)128 * 8192 * 2);   // reused for ADJS B's + Wg5t
  u16*  We1t = (u16*)ab(128 * 2016 * 2);
  u16*  We2t = (u16*)ab(256 * 128 * 2);
  u16*  We3t = (u16*)ab(512 * 256 * 2);
  u16*  Wzt  = (u16*)ab(32 * 512 * 2);
  u16*  Wd1t = (u16*)ab(512 * 32 * 2);
  u16*  Wd2t = (u16*)ab(256 * 512 * 2);
  u16*  Wd3t = (u16*)ab(128 * 256 * 2);
  u16*  Wxt  = (u16*)ab(2000 * 128 * 2);
  u16*  Wg1t = (u16*)ab(128 * 2016 * 2);
  u16*  Wg2t = (u16*)ab(256 * 128 * 2);
  u16*  Wg3t = (u16*)ab(32 * 256 * 2);
  u16*  Wg6t = (u16*)ab(2000 * 128 * 2);
  u16*  W45t = (u16*)ab(128 * 32 * 2);
  u16*  sAt  = (u16*)ab(8192 * 2);
  float* sAtf = (float*)ab(8192 * 4);
  u16*  sBnk = (u16*)ab(8192 * 2);
  float* sBknf = (float*)ab(8192 * 4);
  u16*  sBknb = (u16*)ab(8192 * 2);
  u16*  sBt32 = (u16*)ab(128 * 64 * 2);
  u16*  sBtb  = (u16*)ab(128 * 64 * 2);
  float* sCt = (float*)ab(128 * 128 * 4);
  u16*  sZ1  = (u16*)ab(256 * 32 * 2);
  u16*  sZ2  = (u16*)ab(256 * 64 * 2);
  float* sCt2 = (float*)ab(256 * 256 * 4);
  int*  sfl  = (int*)ab(256);

  const size_t fixedB = (size_t)(cur - (char*)d_ws);
  const size_t P16B = (size_t)16 * 8192 * 128 * 4;
  const size_t P8B  = (size_t)8 * 8192 * 128 * 4;
  const size_t ADJB = (size_t)8192 * 8192 * 2;
  const bool kbig = (fixedB + P16B + ADJB) <= ws_size;
  float* P = (float*)ab(kbig ? P16B : P8B);
  u16* adjb = (u16*)cur;
  const bool use_adjb = ((size_t)(cur - (char*)d_ws) + ADJB) <= ws_size;
  const int KS_ADJ = kbig ? 16 : 8;
  const int KSZ_ADJ = 8192 / KS_ADJ;
  const int KS_2K = kbig ? 16 : 8;
  const int KSZ_2K = kbig ? 128 : 256;

  #define GD(N, M) dim3(((N) + 127) / 128, ((M) + 127) / 128)
  #define MG(MODE, AF, BF, LB, OB, A, LDA, B, LDB, C, LDC, M, N, K, KR, BIAS) \
    mg<MODE, AF, BF, LB, OB><<<GD(N, M), 256, 0, stream>>>( \
        A, LDA, B, LDB, C, LDC, M, N, K, KR, BIAS)
  #define MGS(RMODE, AF, OB, A, LDA, BT, LDB, C, M, N, K, KS, KSZ, PN, BIAS) do { \
    mgs<AF><<<dim3(1, (M) / 128, KS), 256, 0, stream>>>( \
        A, LDA, BT, LDB, P, M, N, K, KSZ, PN); \
    redk<RMODE, OB><<<(((M) * (N)) + 255) / 256, 256, 0, stream>>>( \
        P, KS, PN, C, M, N, BIAS); \
  } while (0)
  #define TR32(S, R, C, LD, D, LDD, KP) \
    tr_k<true><<<dim3(((KP) + 63) / 64, ((C) + 63) / 64), 256, 0, stream>>>( \
        S, R, C, LD, D, LDD, KP)
  #define TRB(S, R, C, LD, D, LDD, KP) \
    tr_k<false><<<dim3(((KP) + 63) / 64, ((C) + 63) / 64), 256, 0, stream>>>( \
        S, R, C, LD, D, LDD, KP)

  // --- self-tests (exact integer arithmetic; sentinel on failure) ---
  st_setup<<<32, 256, 0, stream>>>(sAt, sAtf, sBnk, sBknf, sBknb, sfl);
  MG(0, false, false, 1, false, sAt, 64, sBnk, 64, sCt, 128, 128, 128, 64, 64, nullptr);
  st_check<<<128, 128, 0, stream>>>(sCt, 1, sfl);
  TR32(sBknf, 64, 128, 128, sBt32, 64, 64);
  MG(0, true, false, 1, false, sAtf, 64, sBt32, 64, sCt, 128, 128, 128, 64, 64, nullptr);
  st_check<<<128, 128, 0, stream>>>(sCt, 2, sfl);
  TRB(sBknb, 64, 128, 128, sBtb, 64, 64);
  MGS(0, false, false, sAt, 64, sBtb, 64, sCt, 128, 128, 64, 2, 32, 128, nullptr);
  st_check<<<128, 128, 0, stream>>>(sCt, 8, sfl);
  st2_setup<<<64, 256, 0, stream>>>(sZ1, sZ2);
  gram2<true><<<dim3(2, 2), 256, 0, stream>>>(sZ1, 32, 32, sZ2, 64, 64, sCt2, 256, 256);
  st2_check<<<256, 256, 0, stream>>>(sCt2, sfl);

  // --- one-time weight transposes (f32 [K,N] -> bf16 [N,Kpad]) ---
  TR32(We1, 2000, 128, 128, We1t, 2016, 2016);
  TR32(We2, 128, 256, 256, We2t, 128, 128);
  TR32(We3, 256, 512, 512, We3t, 256, 256);
  TR32(Wz,  512, 20,  20,  Wzt,  512, 512);
  TR32(Wd1, 20,  512, 512, Wd1t, 32,  32);
  TR32(Wd2, 512, 256, 256, Wd2t, 512, 512);
  TR32(Wd3, 256, 128, 128, Wd3t, 256, 256);
  TR32(Wx,  128, 2000, 2000, Wxt, 128, 128);
  TR32(Wg1, 2000, 128, 128, Wg1t, 2016, 2016);
  TR32(Wg2, 128, 256, 256, Wg2t, 128, 128);
  TR32(Wg3, 256, 20,  20,  Wg3t, 256, 256);
  TR32(Wg6, 128, 2000, 2000, Wg6t, 128, 128);

  if (use_adjb)
    f2bf4_k<<<2048, 256, 0, stream>>>(adj, adjb, 16777216L);
  f2bf4_k<<<2048, 256, 0, stream>>>(x, xb, 4096000L);

  // ADJS: transpose the narrow activation to [N,8192] then split-K over adj
  #define ADJS(B, LDB, OUT, N, OB, PN) do { \
    TRB(B, 8192, N, LDB, trB, 8192, 8192); \
    if (use_adjb) MGS(0, false, OB, adjb, 8192, trB, 8192, OUT, 8192, N, 8192, KS_ADJ, KSZ_ADJ, PN, nullptr); \
    else          MGS(0, true,  OB, adj,  8192, trB, 8192, OUT, 8192, N, 8192, KS_ADJ, KSZ_ADJ, PN, nullptr); \
  } while (0)

  // --- AE encoder ---
  MGS(2, false, true, xb, 2000, We1t, 2016, h1, 8192, 128, 2000, KS_2K, KSZ_2K, 128, be1);
  MG(2, false, false, 1, true, h1, 128,  We2t, 128, h2, 256, 8192, 256, 128, 128, be2);
  MG(2, false, false, 1, true, h2, 256,  We3t, 256, h3, 512, 8192, 512, 256, 256, be3);
  MGS(1, false, false, h3, 512, Wzt, 512, zae, 8192, 20, 512, 4, 128, 32, bz);
  copyf_k<<<640, 256, 0, stream>>>(zae, out + OFF_ZAE, 163840);

  // --- SGAE encoder: zsg = adj@((adj@(adj@(x@Wg1)))@Wg2@Wg3) ---
  MGS(0, false, true, xb, 2000, Wg1t, 2016, tA, 8192, 128, 2000, KS_2K, KSZ_2K, 128, nullptr);
  ADJS(tA, 128, tB, 128, true, 128);                // g1
  ADJS(tB, 128, tA, 128, true, 128);                // ag1
  MG(0, false, false, 1, true, tA, 128, Wg2t, 128, tC, 256, 8192, 256, 128, 128, nullptr);
  MGS(0, false, true, tC, 256, Wg3t, 256, t3, 8192, 20, 256, 4, 64, 32, nullptr);
  ADJS(t3, 20, zsg, 20, false, 32);                 // zsg f32
  copyf_k<<<640, 256, 0, stream>>>(zsg, out + OFF_ZSG, 163840);
  padbf_k<<<1024, 256, 0, stream>>>(zsg, zsgb);

  // --- fuse + attention ---
  zi_k<<<640, 256, 0, stream>>>(a, zae, zsg, zib);
  ADJS(zib, 20, zl, 20, false, 32);                 // zl f32
  attn_f<<<1024, 256, 0, stream>>>(zl, gamma, ztp, out + OFF_ZT);

  // --- AE decoder ---
  u16* d1 = h3; u16* d2 = h2; u16* d3 = h1;
  MG(2, false, false, 1, true, ztp, 32, Wd1t, 32, d1, 512, 8192, 512, 32, 32, bd1);
  MG(2, false, false, 1, true, d1, 512, Wd2t, 512, d2, 256, 8192, 256, 512, 512, bd2);
  MGS(2, false, true, d2, 256, Wd3t, 256, d3, 8192, 128, 256, 4, 64, 128, bd3);
  MG(1, false, false, 1, false, d3, 128, Wxt, 128, out + OFF_XHAT, 2000,
     8192, 2000, 128, 128, bx);

  // --- SGAE decoder: z_hat = (adj@(adj@((adj@zt)@(Wg4@Wg5))))@Wg6 ---
  ADJS(ztp, 32, aztp, 32, true, 32);
  u16* Wg5t = trB;   // trB free until next ADJS; Wg5t [128,256] fits easily
  TR32(Wg5, 256, 128, 128, Wg5t, 256, 256);
  MG(0, true, false, 1, false, Wg4, 256, Wg5t, 256, W45, 128, 20, 128, 256, 256, nullptr);
  TR32(W45, 20, 128, 128, W45t, 32, 32);
  u16* u = tA; u16* v = tB;
  MG(0, false, false, 1, true, aztp, 32, W45t, 32, u, 128, 8192, 128, 32, 32, nullptr);
  ADJS(u, 128, v, 128, true, 128);
  ADJS(v, 128, av, 128, true, 128);
  MG(0, false, false, 1, false, av, 128, Wg6t, 128, out + OFF_ZHAT, 2000,
     8192, 2000, 128, 128, nullptr);
  padzhb_k<<<8192, 256, 0, stream>>>(out + OFF_ZHAT, zhb);

  // --- adj_hat = sigmoid(zsg gram) + sigmoid(zhat gram), fused symmetric ---
  gram2<false><<<dim3(64, 64), 256, 0, stream>>>(zsgb, 32, 32, zhb, 2016, 2016,
                                                 out + OFF_ADJ, 8192, 8192);

  // --- soft assignments ---
  softassign_k<true><<<32, 256, 0, stream>>>(ztp, 32, cl, out + OFF_Q);
  softassign_k<false><<<32, 256, 0, stream>>>(zae, 20, cl, out + OFF_Q1);
  softassign_k<false><<<32, 256, 0, stream>>>(zsg, 20, cl, out + OFF_Q2);

  st_probe<<<1, 64, 0, stream>>>(out, sfl);

  #undef GD
  #undef MG
  #undef MGS
  #undef ADJS
  #undef TR32
  #undef TRB
}

// Round 8
// 1190.446 us; speedup vs baseline: 1.3013x; 1.3013x over previous
//
#include <hip/hip_runtime.h>
#include <stdint.h>

typedef unsigned short u16;
typedef short short8 __attribute__((ext_vector_type(8)));
typedef float f32x4 __attribute__((ext_vector_type(4)));
typedef __bf16 bf16x8 __attribute__((ext_vector_type(8)));

#define DEV static __device__ __forceinline__

DEV float bf2f(u16 h) {
  union { unsigned u; float f; } v; v.u = ((unsigned)h) << 16; return v.f;
}
DEV u16 f2bf(float f) {
  union { float f; unsigned u; } v; v.f = f;
  return (u16)((v.u + 0x7fffu + ((v.u >> 16) & 1u)) >> 16);  // RNE
}

// ---------------------------------------------------------------------------
// Transpose to bf16 [C, Kpad]: dst[c][r] = cvt(src[r][c]) for r<R, else 0.
// Turns every GEMM B-operand into the vectorized [N,K] short8 path.
// grid: (ceil(Kpad/64), ceil(C/64)), block 256. Kpad, ldd multiples of 8.
// ---------------------------------------------------------------------------
template<bool F32>
__global__ void tr_k(const void* __restrict__ src, int R, int C, int lds,
                     u16* __restrict__ dst, int ldd, int Kpad)
{
  __shared__ u16 tile[64][72];
  const int t = threadIdx.x;
  const int r0 = blockIdx.x << 6, c0 = blockIdx.y << 6;
  const int sr = t >> 2, sc = (t & 3) << 4;
  #pragma unroll
  for (int j = 0; j < 16; ++j) {
    const int r = r0 + sr, c = c0 + sc + j;
    u16 v = 0;
    if (r < R && c < C)
      v = F32 ? f2bf(((const float*)src)[(size_t)r * lds + c])
              : ((const u16*)src)[(size_t)r * lds + c];
    tile[sr][sc + j] = v;
  }
  __syncthreads();
  const int dc = t >> 2, dr = (t & 3) << 4;
  const int gc = c0 + dc;
  if (gc < C) {
    #pragma unroll
    for (int h = 0; h < 2; ++h) {
      const int gr = r0 + dr + (h << 3);
      if (gr < Kpad) {                 // gr, Kpad both mult of 8
        short8 o;
        #pragma unroll
        for (int j = 0; j < 8; ++j) o[j] = (short)tile[dr + (h << 3) + j][dc];
        *(short8*)&dst[(size_t)gc * ldd + gr] = o;
      }
    }
  }
}

// ---------------------------------------------------------------------------
// MFMA GEMM: C[M,N] = act(A @ B + bias), f32 accumulate, software-pipelined
// staging. A row-major [M,K] f32/bf16; B: LB=0 [K,N] (legacy) / LB=1 [N,K].
// MODE: 0 plain,1 +bias,2 lrelu,3 sigmoid. OUTBF: bf16 C.
// ---------------------------------------------------------------------------
template<int MODE, bool AF32, bool BF32, int LB, bool OUTBF>
__global__ __launch_bounds__(256, 2) void mg(
    const void* __restrict__ Av, int lda,
    const void* __restrict__ Bv, int ldb,
    void* __restrict__ Cv, int ldc,
    int M, int N, int K, int Kreal,
    const float* __restrict__ bias)
{
  __shared__ u16 As[128 * 40];
  __shared__ u16 Bs[128 * 40];
  const int t = threadIdx.x;
  const int w = t >> 6, l = t & 63;
  const int l15 = l & 15, lhi = l >> 4;
  const int bm = blockIdx.y << 7, bn = blockIdx.x << 7;
  const int wm = (w >> 1) << 6, wn = (w & 1) << 6;
  const int srow = t >> 2, scol = (t & 3) << 3;
  const int bcol = t & 127, bkh = (t >> 7) << 4;

  f32x4 acc[4][4] = {};
  short8 pa[2], pb[2];

  auto LDA_ = [&](int kt) {
    #pragma unroll
    for (int c = 0; c < 2; ++c) {
      const int gc = kt + scol;
      short8 v = {};
      const int ga = bm + srow + (c << 6);
      if ((gc + 8 <= K) && ga < M) {
        if (AF32) {
          const float* p = (const float*)Av + (size_t)ga * lda + gc;
          #pragma unroll
          for (int j = 0; j < 8; ++j) v[j] = (short)f2bf(p[j]);
        } else {
          v = *(const short8*)((const u16*)Av + (size_t)ga * lda + gc);
        }
      }
      pa[c] = v;
    }
  };
  auto LDB_ = [&](int kt) {
    if (LB == 1) {
      #pragma unroll
      for (int c = 0; c < 2; ++c) {
        const int gc = kt + scol;
        short8 v = {};
        const int gn = bn + srow + (c << 6);
        if ((gc + 8 <= K) && gn < N) {
          if (BF32) {
            const float* p = (const float*)Bv + (size_t)gn * ldb + gc;
            #pragma unroll
            for (int j = 0; j < 8; ++j) v[j] = (short)f2bf(p[j]);
          } else {
            v = *(const short8*)((const u16*)Bv + (size_t)gn * ldb + gc);
          }
        }
        pb[c] = v;
      }
    } else {
      #pragma unroll
      for (int h = 0; h < 2; ++h) {
        const int k0 = bkh + (h << 3);
        short8 v = {};
        const int gn = bn + bcol;
        if (gn < N) {
          #pragma unroll
          for (int j = 0; j < 8; ++j) {
            const int gk = kt + k0 + j;
            if (gk < Kreal) {
              if (BF32) v[j] = (short)f2bf(((const float*)Bv)[(size_t)gk * ldb + gn]);
              else      v[j] = (short)((const u16*)Bv)[(size_t)gk * ldb + gn];
            }
          }
        }
        pb[h] = v;
      }
    }
  };

  LDA_(0); LDB_(0);
  for (int kt = 0; kt < K; kt += 32) {
    #pragma unroll
    for (int c = 0; c < 2; ++c)
      *(short8*)&As[(srow + (c << 6)) * 40 + scol] = pa[c];
    if (LB == 1) {
      #pragma unroll
      for (int c = 0; c < 2; ++c)
        *(short8*)&Bs[(srow + (c << 6)) * 40 + scol] = pb[c];
    } else {
      #pragma unroll
      for (int h = 0; h < 2; ++h)
        *(short8*)&Bs[bcol * 40 + bkh + (h << 3)] = pb[h];
    }
    __syncthreads();
    if (kt + 32 < K) { LDA_(kt + 32); LDB_(kt + 32); }
    short8 af[4], bfr[4];
    #pragma unroll
    for (int m = 0; m < 4; ++m)
      af[m] = *(const short8*)&As[(wm + (m << 4) + l15) * 40 + (lhi << 3)];
    #pragma unroll
    for (int n = 0; n < 4; ++n)
      bfr[n] = *(const short8*)&Bs[(wn + (n << 4) + l15) * 40 + (lhi << 3)];
    #pragma unroll
    for (int m = 0; m < 4; ++m) {
      #pragma unroll
      for (int n = 0; n < 4; ++n)
        acc[m][n] = __builtin_amdgcn_mfma_f32_16x16x32_bf16(
            __builtin_bit_cast(bf16x8, af[m]),
            __builtin_bit_cast(bf16x8, bfr[n]), acc[m][n], 0, 0, 0);
    }
    __syncthreads();
  }

  #pragma unroll
  for (int m = 0; m < 4; ++m) {
    #pragma unroll
    for (int n = 0; n < 4; ++n) {
      #pragma unroll
      for (int r = 0; r < 4; ++r) {
        const int row = bm + wm + (m << 4) + (lhi << 2) + r;
        const int col = bn + wn + (n << 4) + l15;
        if (row < M && col < N) {
          const float v0 = acc[m][n][r];
          float o;
          if (MODE == 0) o = v0;
          else if (MODE == 1) o = v0 + bias[col];
          else if (MODE == 2) { const float s = v0 + bias[col]; o = (s > 0.f) ? s : 0.2f * s; }
          else o = 1.f / (1.f + __expf(-v0));
          if (OUTBF) ((u16*)Cv)[(size_t)row * ldc + col] = f2bf(o);
          else       ((float*)Cv)[(size_t)row * ldc + col] = o;
        }
      }
    }
  }
}

// ---------------------------------------------------------------------------
// Split-K MFMA GEMM (narrow N<=128). B is ALWAYS bf16 B^T [N,K] (vectorized
// short8 loads — the scalar column-gather path is gone).
// Grid (1, M/128, KS); partials P[z][row][0..PN).
// ---------------------------------------------------------------------------
template<bool AF32>
__global__ __launch_bounds__(256, 2) void mgs(
    const void* __restrict__ Av, int lda,
    const u16* __restrict__ Bt, int ldb,
    float* __restrict__ P,
    int M, int N, int K, int KSZ, int PN)
{
  __shared__ u16 As[128 * 40];
  __shared__ u16 Bs[128 * 40];
  const int t = threadIdx.x;
  const int w = t >> 6, l = t & 63;
  const int l15 = l & 15, lhi = l >> 4;
  const int bm = blockIdx.y << 7;
  const int wm = (w >> 1) << 6, wn = (w & 1) << 6;
  const int srow = t >> 2, scol = (t & 3) << 3;
  const int kbeg = blockIdx.z * KSZ;
  const int kend = min(K, kbeg + KSZ);

  f32x4 acc[4][4] = {};
  short8 pa[2], pb[2];

  auto LDA_ = [&](int kt) {
    #pragma unroll
    for (int c = 0; c < 2; ++c) {
      const int gc = kt + scol;
      short8 v = {};
      const int ga = bm + srow + (c << 6);
      if ((gc + 8 <= K) && ga < M) {
        if (AF32) {
          const float* p = (const float*)Av + (size_t)ga * lda + gc;
          #pragma unroll
          for (int j = 0; j < 8; ++j) v[j] = (short)f2bf(p[j]);
        } else {
          v = *(const short8*)((const u16*)Av + (size_t)ga * lda + gc);
        }
      }
      pa[c] = v;
    }
  };
  auto LDB_ = [&](int kt) {
    #pragma unroll
    for (int c = 0; c < 2; ++c) {
      const int gc = kt + scol;
      short8 v = {};
      const int gn = srow + (c << 6);
      if ((gc + 8 <= K) && gn < N)
        v = *(const short8*)(Bt + (size_t)gn * ldb + gc);
      pb[c] = v;
    }
  };

  LDA_(kbeg); LDB_(kbeg);
  for (int kt = kbeg; kt < kend; kt += 32) {
    #pragma unroll
    for (int c = 0; c < 2; ++c)
      *(short8*)&As[(srow + (c << 6)) * 40 + scol] = pa[c];
    #pragma unroll
    for (int c = 0; c < 2; ++c)
      *(short8*)&Bs[(srow + (c << 6)) * 40 + scol] = pb[c];
    __syncthreads();
    if (kt + 32 < kend) { LDA_(kt + 32); LDB_(kt + 32); }
    short8 af[4], bfr[4];
    #pragma unroll
    for (int m = 0; m < 4; ++m)
      af[m] = *(const short8*)&As[(wm + (m << 4) + l15) * 40 + (lhi << 3)];
    #pragma unroll
    for (int n = 0; n < 4; ++n)
      bfr[n] = *(const short8*)&Bs[(wn + (n << 4) + l15) * 40 + (lhi << 3)];
    #pragma unroll
    for (int m = 0; m < 4; ++m) {
      #pragma unroll
      for (int n = 0; n < 4; ++n)
        acc[m][n] = __builtin_amdgcn_mfma_f32_16x16x32_bf16(
            __builtin_bit_cast(bf16x8, af[m]),
            __builtin_bit_cast(bf16x8, bfr[n]), acc[m][n], 0, 0, 0);
    }
    __syncthreads();
  }

  float* Pz = P + (size_t)blockIdx.z * M * PN;
  #pragma unroll
  for (int m = 0; m < 4; ++m) {
    #pragma unroll
    for (int n = 0; n < 4; ++n) {
      const int col = wn + (n << 4) + l15;
      if (col < PN) {
        #pragma unroll
        for (int r = 0; r < 4; ++r) {
          const int row = bm + wm + (m << 4) + (lhi << 2) + r;
          Pz[(size_t)row * PN + col] = acc[m][n][r];
        }
      }
    }
  }
}

template<int MODE, bool OUTBF>
__global__ void redk(const float* __restrict__ P, int KS, int PN,
                     void* __restrict__ Cv, int M, int N,
                     const float* __restrict__ bias)
{
  const int i = blockIdx.x * 256 + threadIdx.x;
  if (i >= M * N) return;
  const int row = i / N, col = i - row * N;
  float s = 0.f;
  for (int z = 0; z < KS; ++z) s += P[((size_t)z * M + row) * PN + col];
  float o;
  if (MODE == 0) o = s;
  else if (MODE == 1) o = s + bias[col];
  else { const float b = s + bias[col]; o = (b > 0.f) ? b : 0.2f * b; }
  if (OUTBF) ((u16*)Cv)[i] = f2bf(o);
  else       ((float*)Cv)[i] = o;
}

// ---------------------------------------------------------------------------
// Fused symmetric dual gram — EXACT r4 structure (best measured: 330us).
// Reg-staged LDS, stride-40 rows, 1-step reg prefetch, 2 barriers/step,
// identity block mapping, __launch_bounds__(256,2), VGPR 96.
// r5 (2-deep prefetch), r6 (XCD swizzle), r7 (occupancy bound) all regressed
// — this is a sharp local optimum; do not touch the K-loop.
// ---------------------------------------------------------------------------
template<bool TEST>
__global__ __launch_bounds__(256, 2) void gram2(
    const u16* __restrict__ Z1, int ld1, int K1,
    const u16* __restrict__ Z2, int ld2, int K2,
    float* __restrict__ C, int ldc, int M)
{
  __shared__ union SM {
    u16 stage[2][128 * 40];
    float tb[32][132];
  } sm;
  const int bx = blockIdx.x, by = blockIdx.y;
  if (bx < by) return;
  u16* As = sm.stage[0];
  u16* Bs = sm.stage[1];
  const int t = threadIdx.x;
  const int w = t >> 6, l = t & 63;
  const int l15 = l & 15, lhi = l >> 4;
  const int bm = by << 7, bn = bx << 7;
  const int wm = (w >> 1) << 6, wn = (w & 1) << 6;
  const int srow = t >> 2, scol = (t & 3) << 3;

  f32x4 acc1[4][4] = {};
  f32x4 acc2[4][4] = {};
  short8 va0, va1, vb0, vb1;

  auto LOD = [&](const u16* Z, int ld, int KK, int kt) {
    short8 a0 = {}, a1 = {}, b0 = {}, b1 = {};
    const int gc = kt + scol;
    if (gc + 8 <= KK) {
      a0 = *(const short8*)(Z + (size_t)(bm + srow) * ld + gc);
      a1 = *(const short8*)(Z + (size_t)(bm + srow + 64) * ld + gc);
      b0 = *(const short8*)(Z + (size_t)(bn + srow) * ld + gc);
      b1 = *(const short8*)(Z + (size_t)(bn + srow + 64) * ld + gc);
    }
    va0 = a0; va1 = a1; vb0 = b0; vb1 = b1;
  };
  auto STORE = [&]() {
    *(short8*)&As[srow * 40 + scol] = va0;
    *(short8*)&As[(srow + 64) * 40 + scol] = va1;
    *(short8*)&Bs[srow * 40 + scol] = vb0;
    *(short8*)&Bs[(srow + 64) * 40 + scol] = vb1;
  };
  auto FMM = [&](f32x4 (&ACC)[4][4]) {
    short8 af[4], bfr[4];
    #pragma unroll
    for (int m = 0; m < 4; ++m)
      af[m] = *(const short8*)&As[(wm + (m << 4) + l15) * 40 + (lhi << 3)];
    #pragma unroll
    for (int n = 0; n < 4; ++n)
      bfr[n] = *(const short8*)&Bs[(wn + (n << 4) + l15) * 40 + (lhi << 3)];
    #pragma unroll
    for (int m = 0; m < 4; ++m) {
      #pragma unroll
      for (int n = 0; n < 4; ++n)
        ACC[m][n] = __builtin_amdgcn_mfma_f32_16x16x32_bf16(
            __builtin_bit_cast(bf16x8, af[m]),
            __builtin_bit_cast(bf16x8, bfr[n]), ACC[m][n], 0, 0, 0);
    }
  };

  LOD(Z1, ld1, K1, 0);
  for (int kt = 0; kt < K1; kt += 32) {
    STORE();
    __syncthreads();
    if (kt + 32 < K1) LOD(Z1, ld1, K1, kt + 32);
    else LOD(Z2, ld2, K2, 0);
    FMM(acc1);
    __syncthreads();
  }
  for (int kt = 0; kt < K2; kt += 32) {
    STORE();
    __syncthreads();
    if (kt + 32 < K2) LOD(Z2, ld2, K2, kt + 32);
    FMM(acc2);
    __syncthreads();
  }

  auto cval = [&](int m, int n, int r) -> float {
    const float a1 = acc1[m][n][r], a2 = acc2[m][n][r];
    if (TEST) return a1 + a2;
    return 1.f / (1.f + __expf(-a1)) + 1.f / (1.f + __expf(-a2));
  };

  #pragma unroll
  for (int m = 0; m < 4; ++m) {
    #pragma unroll
    for (int n = 0; n < 4; ++n) {
      #pragma unroll
      for (int r = 0; r < 4; ++r) {
        const int row = bm + wm + (m << 4) + (lhi << 2) + r;
        const int col = bn + wn + (n << 4) + l15;
        C[(size_t)row * ldc + col] = cval(m, n, r);
      }
    }
  }

  if (bx != by) {
    #pragma unroll
    for (int p = 0; p < 4; ++p) {
      __syncthreads();
      if (wn == ((p & 2) << 5)) {
        #pragma unroll
        for (int n2 = 0; n2 < 2; ++n2) {
          const int n = ((p & 1) << 1) + n2;
          #pragma unroll
          for (int m = 0; m < 4; ++m)
            #pragma unroll
            for (int r = 0; r < 4; ++r)
              sm.tb[(n2 << 4) + l15][wm + (m << 4) + (lhi << 2) + r] = cval(m, n, r);
        }
      }
      __syncthreads();
      #pragma unroll
      for (int i = 0; i < 16; ++i) {
        const int e = t + (i << 8);
        const int rr = e >> 7, cc = e & 127;
        C[(size_t)(bn + (p << 5) + rr) * ldc + bm + cc] = sm.tb[rr][cc];
      }
    }
  }
}

// --------------------------- small kernels ---------------------------------
__global__ void zi_k(const float* __restrict__ a, const float* __restrict__ zae,
                     const float* __restrict__ zsg, u16* __restrict__ zi)
{
  const int i = blockIdx.x * 256 + threadIdx.x;
  if (i < 163840) {
    const float av = a[i];
    zi[i] = f2bf(av * zae[i] + (1.f - av) * zsg[i]);
  }
}

__global__ void copyf_k(const float* __restrict__ src, float* __restrict__ dst, int n)
{
  const int i = blockIdx.x * 256 + threadIdx.x;
  if (i < n) dst[i] = src[i];
}

__global__ void f2bf4_k(const float* __restrict__ s, u16* __restrict__ d, long n4)
{
  long i = (long)blockIdx.x * 256 + threadIdx.x;
  const long stride = (long)gridDim.x * 256;
  for (; i < n4; i += stride) {
    const float4 v = ((const float4*)s)[i];
    union { u16 h[4]; unsigned long long u; } o;
    o.h[0] = f2bf(v.x); o.h[1] = f2bf(v.y); o.h[2] = f2bf(v.z); o.h[3] = f2bf(v.w);
    ((unsigned long long*)d)[i] = o.u;
  }
}

// 8192 x 2000 f32 -> 8192 x 2016 bf16, zero pad cols [2000,2016).
__global__ void padzhb_k(const float* __restrict__ s, u16* __restrict__ d)
{
  const int row = blockIdx.x;
  for (int g = threadIdx.x; g < 504; g += 256) {
    const int c4 = g << 2;
    union { u16 h[4]; unsigned long long u; } o;
    if (c4 < 2000) {
      const float4 v = *(const float4*)(s + (size_t)row * 2000 + c4);
      o.h[0] = f2bf(v.x); o.h[1] = f2bf(v.y); o.h[2] = f2bf(v.z); o.h[3] = f2bf(v.w);
    } else {
      o.u = 0ULL;
    }
    *(unsigned long long*)(d + (size_t)row * 2016 + c4) = o.u;
  }
}

__global__ void padbf_k(const float* __restrict__ s, u16* __restrict__ d)
{
  const int i = blockIdx.x * 256 + threadIdx.x;
  const int row = i >> 5, col = i & 31;
  d[i] = (col < 20) ? f2bf(s[row * 20 + col]) : (u16)0;
}

__global__ __launch_bounds__(256) void attn_f(const float* __restrict__ zl,
                                              const float* __restrict__ gammap,
                                              u16* __restrict__ ztp,
                                              float* __restrict__ ztout)
{
  __shared__ float tile[256 * 20];
  const int t = threadIdx.x;
  const int sub = t & 31;
  const int row = blockIdx.x * 8 + (t >> 5);
  float qv[20];
  #pragma unroll
  for (int k = 0; k < 20; ++k) qv[k] = zl[(size_t)row * 20 + k];
  float m = -1e30f, ssum = 0.f;
  float acc[20] = {};
  for (int j0 = 0; j0 < 8192; j0 += 256) {
    #pragma unroll
    for (int k = 0; k < 20; ++k) tile[t * 20 + k] = zl[(size_t)(j0 + t) * 20 + k];
    __syncthreads();
    for (int jj = 0; jj < 8; ++jj) {
      const int jl = (jj << 5) + sub;
      float s = 0.f;
      #pragma unroll
      for (int k = 0; k < 20; ++k) s += qv[k] * tile[jl * 20 + k];
      if (s > m) {
        const float sc = __expf(m - s);
        ssum *= sc;
        #pragma unroll
        for (int k = 0; k < 20; ++k) acc[k] *= sc;
        m = s;
      }
      const float p = __expf(s - m);
      ssum += p;
      #pragma unroll
      for (int k = 0; k < 20; ++k) acc[k] += p * tile[jl * 20 + k];
    }
    __syncthreads();
  }
  #pragma unroll
  for (int off = 16; off >= 1; off >>= 1) {
    const float mo = __shfl_xor(m, off, 32);
    const float so = __shfl_xor(ssum, off, 32);
    const float nm = fmaxf(m, mo);
    const float e1 = __expf(m - nm), e2 = __expf(mo - nm);
    ssum = ssum * e1 + so * e2;
    #pragma unroll
    for (int k = 0; k < 20; ++k) {
      const float ao = __shfl_xor(acc[k], off, 32);
      acc[k] = acc[k] * e1 + ao * e2;
    }
    m = nm;
  }
  if (sub == 0) {
    const float g = gammap[0];
    #pragma unroll
    for (int k = 0; k < 20; ++k) {
      const float v = g * (acc[k] / ssum) + qv[k];
      ztout[(size_t)row * 20 + k] = v;
      ztp[(size_t)row * 32 + k] = f2bf(v);
    }
    #pragma unroll
    for (int k = 20; k < 32; ++k) ztp[(size_t)row * 32 + k] = 0;
  }
}

template<bool BFIN>
__global__ void softassign_k(const void* __restrict__ zp, int stride,
                             const float* __restrict__ cl, float* __restrict__ outq)
{
  const int i = blockIdx.x * 256 + threadIdx.x;
  float zv[20];
  #pragma unroll
  for (int k = 0; k < 20; ++k)
    zv[k] = BFIN ? bf2f(((const u16*)zp)[(size_t)i * stride + k])
                 : ((const float*)zp)[(size_t)i * stride + k];
  float qv[10], s = 0.f;
  #pragma unroll
  for (int j = 0; j < 10; ++j) {
    float d2 = 0.f;
    #pragma unroll
    for (int k = 0; k < 20; ++k) { const float d = zv[k] - cl[j * 20 + k]; d2 += d * d; }
    qv[j] = 1.f / (1.f + d2);
    s += qv[j];
  }
  const float inv = 1.f / s;
  #pragma unroll
  for (int j = 0; j < 10; ++j) outq[(size_t)i * 10 + j] = qv[j] * inv;
}

// --------------------------- self-test -------------------------------------
DEV float stA(int i, int k) { return (float)(((i * 5 + k * 7) % 3) - 1); }
DEV float stB(int j, int k) { return (float)(((j * 11 + k * 13) % 5) - 2); }

__global__ void st_setup(u16* At, float* Atf, u16* Bnk, float* Bknf, u16* Bknb, int* fl)
{
  const int idx = blockIdx.x * 256 + threadIdx.x;
  { const int i = idx >> 6, k = idx & 63;
    At[idx] = f2bf(stA(i, k)); Atf[idx] = stA(i, k);
    Bnk[idx] = f2bf(stB(i, k)); }
  { const int k = idx >> 7, j = idx & 127;
    Bknf[idx] = stB(j, k); Bknb[idx] = f2bf(stB(j, k)); }
  if (idx == 0) *fl = 0;
}

__global__ void st_check(const float* C, int bit, int* fl)
{
  const int i = blockIdx.x, j = threadIdx.x;
  float ref = 0.f;
  for (int k = 0; k < 64; ++k) ref += stA(i, k) * stB(j, k);
  if (C[i * 128 + j] != ref) atomicOr(fl, bit);
}

__global__ void st2_setup(u16* Z1, u16* Z2)
{
  const int idx = blockIdx.x * 256 + threadIdx.x;
  if (idx < 8192)  { const int i = idx >> 5, k = idx & 31; Z1[idx] = f2bf(stA(i, k)); }
  if (idx < 16384) { const int i = idx >> 6, k = idx & 63; Z2[idx] = f2bf(stB(i, k)); }
}

__global__ void st2_check(const float* C, int* fl)
{
  const int i = blockIdx.x, j = threadIdx.x;
  float ref = 0.f;
  for (int k = 0; k < 32; ++k) ref += stA(i, k) * stA(j, k);
  for (int k = 0; k < 64; ++k) ref += stB(i, k) * stB(j, k);
  if (C[i * 256 + j] != ref) atomicOr(fl, 16);
}

__global__ void st_probe(float* out0, const int* fl)
{
  if (threadIdx.x == 0 && blockIdx.x == 0 && *fl) *out0 = 4096.f + (float)(*fl);
}

// ---------------------------------------------------------------------------
extern "C" void kernel_launch(void* const* d_in, const int* in_sizes, int n_in,
                              void* d_out, int out_size, void* d_ws, size_t ws_size,
                              hipStream_t stream)
{
  (void)in_sizes; (void)n_in; (void)out_size;
  const float* x     = (const float*)d_in[0];
  const float* adj   = (const float*)d_in[1];
  const float* a     = (const float*)d_in[2];
  const float* cl    = (const float*)d_in[3];
  const float* gamma = (const float*)d_in[4];
  const float* We1 = (const float*)d_in[5];  const float* be1 = (const float*)d_in[6];
  const float* We2 = (const float*)d_in[7];  const float* be2 = (const float*)d_in[8];
  const float* We3 = (const float*)d_in[9];  const float* be3 = (const float*)d_in[10];
  const float* Wz  = (const float*)d_in[11]; const float* bz  = (const float*)d_in[12];
  const float* Wd1 = (const float*)d_in[13]; const float* bd1 = (const float*)d_in[14];
  const float* Wd2 = (const float*)d_in[15]; const float* bd2 = (const float*)d_in[16];
  const float* Wd3 = (const float*)d_in[17]; const float* bd3 = (const float*)d_in[18];
  const float* Wx  = (const float*)d_in[19]; const float* bx  = (const float*)d_in[20];
  const float* Wg1 = (const float*)d_in[21];
  const float* Wg2 = (const float*)d_in[22];
  const float* Wg3 = (const float*)d_in[23];
  const float* Wg4 = (const float*)d_in[24];
  const float* Wg5 = (const float*)d_in[25];
  const float* Wg6 = (const float*)d_in[26];
  float* out = (float*)d_out;

  const size_t OFF_XHAT = 0;
  const size_t OFF_ZHAT = 16384000;
  const size_t OFF_ADJ  = 32768000;
  const size_t OFF_ZAE  = 99876864;
  const size_t OFF_ZSG  = 100040704;
  const size_t OFF_Q    = 100204544;
  const size_t OFF_Q1   = 100286464;
  const size_t OFF_Q2   = 100368384;
  const size_t OFF_ZT   = 100450304;

  char* cur = (char*)d_ws;
  auto ab = [&](size_t bytes) {
    char* p = cur;
    cur += ((bytes + 255) & ~(size_t)255);
    return p;
  };
  u16*  h1   = (u16*)ab(8192 * 128 * 2);
  u16*  h2   = (u16*)ab(8192 * 256 * 2);
  u16*  h3   = (u16*)ab(8192 * 512 * 2);
  u16*  tA   = (u16*)ab(8192 * 128 * 2);
  u16*  tB   = (u16*)ab(8192 * 128 * 2);
  u16*  tC   = (u16*)ab(8192 * 256 * 2);
  u16*  av   = (u16*)ab(8192 * 128 * 2);
  u16*  t3   = (u16*)ab(8192 * 20 * 2);
  float* zae = (float*)ab(8192 * 20 * 4);
  float* zsg = (float*)ab(8192 * 20 * 4);
  u16*  zsgb = (u16*)ab(8192 * 32 * 2);
  u16*  zib  = (u16*)ab(8192 * 20 * 2);
  float* zl  = (float*)ab(8192 * 20 * 4);
  u16*  ztp  = (u16*)ab(8192 * 32 * 2);
  u16*  aztp = (u16*)ab(8192 * 32 * 2);
  float* W45 = (float*)ab(20 * 128 * 4);
  u16*  zhb  = (u16*)ab((size_t)8192 * 2016 * 2);
  u16*  xb   = (u16*)ab((size_t)8192 * 2000 * 2);
  // transposed-B operands (bf16 [N,K])
  u16*  trB  = (u16*)ab((size_t)128 * 8192 * 2);   // reused for ADJS B's + Wg5t
  u16*  We1t = (u16*)ab(128 * 2016 * 2);
  u16*  We2t = (u16*)ab(256 * 128 * 2);
  u16*  We3t = (u16*)ab(512 * 256 * 2);
  u16*  Wzt  = (u16*)ab(32 * 512 * 2);
  u16*  Wd1t = (u16*)ab(512 * 32 * 2);
  u16*  Wd2t = (u16*)ab(256 * 512 * 2);
  u16*  Wd3t = (u16*)ab(128 * 256 * 2);
  u16*  Wxt  = (u16*)ab(2000 * 128 * 2);
  u16*  Wg1t = (u16*)ab(128 * 2016 * 2);
  u16*  Wg2t = (u16*)ab(256 * 128 * 2);
  u16*  Wg3t = (u16*)ab(32 * 256 * 2);
  u16*  Wg6t = (u16*)ab(2000 * 128 * 2);
  u16*  W45t = (u16*)ab(128 * 32 * 2);
  u16*  sAt  = (u16*)ab(8192 * 2);
  float* sAtf = (float*)ab(8192 * 4);
  u16*  sBnk = (u16*)ab(8192 * 2);
  float* sBknf = (float*)ab(8192 * 4);
  u16*  sBknb = (u16*)ab(8192 * 2);
  u16*  sBt32 = (u16*)ab(128 * 64 * 2);
  u16*  sBtb  = (u16*)ab(128 * 64 * 2);
  float* sCt = (float*)ab(128 * 128 * 4);
  u16*  sZ1  = (u16*)ab(256 * 32 * 2);
  u16*  sZ2  = (u16*)ab(256 * 64 * 2);
  float* sCt2 = (float*)ab(256 * 256 * 4);
  int*  sfl  = (int*)ab(256);

  const size_t fixedB = (size_t)(cur - (char*)d_ws);
  const size_t P16B = (size_t)16 * 8192 * 128 * 4;
  const size_t P8B  = (size_t)8 * 8192 * 128 * 4;
  const size_t ADJB = (size_t)8192 * 8192 * 2;
  const bool kbig = (fixedB + P16B + ADJB) <= ws_size;
  float* P = (float*)ab(kbig ? P16B : P8B);
  u16* adjb = (u16*)cur;
  const bool use_adjb = ((size_t)(cur - (char*)d_ws) + ADJB) <= ws_size;
  // KS=8 everywhere (was 16 in the kbig path): halves split-K partial
  // traffic (P write + redk read ~1.4GB -> 0.7GB) at identical residency
  // (512 blocks = 2/CU exactly). The !kbig path already ran KS=8.
  const int KS_ADJ = 8;
  const int KSZ_ADJ = 1024;
  const int KS_2K = 8;
  const int KSZ_2K = 256;

  #define GD(N, M) dim3(((N) + 127) / 128, ((M) + 127) / 128)
  #define MG(MODE, AF, BF, LB, OB, A, LDA, B, LDB, C, LDC, M, N, K, KR, BIAS) \
    mg<MODE, AF, BF, LB, OB><<<GD(N, M), 256, 0, stream>>>( \
        A, LDA, B, LDB, C, LDC, M, N, K, KR, BIAS)
  #define MGS(RMODE, AF, OB, A, LDA, BT, LDB, C, M, N, K, KS, KSZ, PN, BIAS) do { \
    mgs<AF><<<dim3(1, (M) / 128, KS), 256, 0, stream>>>( \
        A, LDA, BT, LDB, P, M, N, K, KSZ, PN); \
    redk<RMODE, OB><<<(((M) * (N)) + 255) / 256, 256, 0, stream>>>( \
        P, KS, PN, C, M, N, BIAS); \
  } while (0)
  #define TR32(S, R, C, LD, D, LDD, KP) \
    tr_k<true><<<dim3(((KP) + 63) / 64, ((C) + 63) / 64), 256, 0, stream>>>( \
        S, R, C, LD, D, LDD, KP)
  #define TRB(S, R, C, LD, D, LDD, KP) \
    tr_k<false><<<dim3(((KP) + 63) / 64, ((C) + 63) / 64), 256, 0, stream>>>( \
        S, R, C, LD, D, LDD, KP)

  // --- self-tests (exact integer arithmetic; sentinel on failure) ---
  st_setup<<<32, 256, 0, stream>>>(sAt, sAtf, sBnk, sBknf, sBknb, sfl);
  MG(0, false, false, 1, false, sAt, 64, sBnk, 64, sCt, 128, 128, 128, 64, 64, nullptr);
  st_check<<<128, 128, 0, stream>>>(sCt, 1, sfl);
  TR32(sBknf, 64, 128, 128, sBt32, 64, 64);
  MG(0, true, false, 1, false, sAtf, 64, sBt32, 64, sCt, 128, 128, 128, 64, 64, nullptr);
  st_check<<<128, 128, 0, stream>>>(sCt, 2, sfl);
  TRB(sBknb, 64, 128, 128, sBtb, 64, 64);
  MGS(0, false, false, sAt, 64, sBtb, 64, sCt, 128, 128, 64, 2, 32, 128, nullptr);
  st_check<<<128, 128, 0, stream>>>(sCt, 8, sfl);
  st2_setup<<<64, 256, 0, stream>>>(sZ1, sZ2);
  gram2<true><<<dim3(2, 2), 256, 0, stream>>>(sZ1, 32, 32, sZ2, 64, 64, sCt2, 256, 256);
  st2_check<<<256, 256, 0, stream>>>(sCt2, sfl);

  // --- one-time weight transposes (f32 [K,N] -> bf16 [N,Kpad]) ---
  TR32(We1, 2000, 128, 128, We1t, 2016, 2016);
  TR32(We2, 128, 256, 256, We2t, 128, 128);
  TR32(We3, 256, 512, 512, We3t, 256, 256);
  TR32(Wz,  512, 20,  20,  Wzt,  512, 512);
  TR32(Wd1, 20,  512, 512, Wd1t, 32,  32);
  TR32(Wd2, 512, 256, 256, Wd2t, 512, 512);
  TR32(Wd3, 256, 128, 128, Wd3t, 256, 256);
  TR32(Wx,  128, 2000, 2000, Wxt, 128, 128);
  TR32(Wg1, 2000, 128, 128, Wg1t, 2016, 2016);
  TR32(Wg2, 128, 256, 256, Wg2t, 128, 128);
  TR32(Wg3, 256, 20,  20,  Wg3t, 256, 256);
  TR32(Wg6, 128, 2000, 2000, Wg6t, 128, 128);

  if (use_adjb)
    f2bf4_k<<<2048, 256, 0, stream>>>(adj, adjb, 16777216L);
  f2bf4_k<<<2048, 256, 0, stream>>>(x, xb, 4096000L);

  // ADJS: transpose the narrow activation to [N,8192] then split-K over adj
  #define ADJS(B, LDB, OUT, N, OB, PN) do { \
    TRB(B, 8192, N, LDB, trB, 8192, 8192); \
    if (use_adjb) MGS(0, false, OB, adjb, 8192, trB, 8192, OUT, 8192, N, 8192, KS_ADJ, KSZ_ADJ, PN, nullptr); \
    else          MGS(0, true,  OB, adj,  8192, trB, 8192, OUT, 8192, N, 8192, KS_ADJ, KSZ_ADJ, PN, nullptr); \
  } while (0)

  // --- AE encoder ---
  MGS(2, false, true, xb, 2000, We1t, 2016, h1, 8192, 128, 2000, KS_2K, KSZ_2K, 128, be1);
  MG(2, false, false, 1, true, h1, 128,  We2t, 128, h2, 256, 8192, 256, 128, 128, be2);
  MG(2, false, false, 1, true, h2, 256,  We3t, 256, h3, 512, 8192, 512, 256, 256, be3);
  MGS(1, false, false, h3, 512, Wzt, 512, zae, 8192, 20, 512, 4, 128, 32, bz);
  copyf_k<<<640, 256, 0, stream>>>(zae, out + OFF_ZAE, 163840);

  // --- SGAE encoder: zsg = adj@((adj@(adj@(x@Wg1)))@Wg2@Wg3) ---
  MGS(0, false, true, xb, 2000, Wg1t, 2016, tA, 8192, 128, 2000, KS_2K, KSZ_2K, 128, nullptr);
  ADJS(tA, 128, tB, 128, true, 128);                // g1
  ADJS(tB, 128, tA, 128, true, 128);                // ag1
  MG(0, false, false, 1, true, tA, 128, Wg2t, 128, tC, 256, 8192, 256, 128, 128, nullptr);
  MGS(0, false, true, tC, 256, Wg3t, 256, t3, 8192, 20, 256, 4, 64, 32, nullptr);
  ADJS(t3, 20, zsg, 20, false, 32);                 // zsg f32
  copyf_k<<<640, 256, 0, stream>>>(zsg, out + OFF_ZSG, 163840);
  padbf_k<<<1024, 256, 0, stream>>>(zsg, zsgb);

  // --- fuse + attention ---
  zi_k<<<640, 256, 0, stream>>>(a, zae, zsg, zib);
  ADJS(zib, 20, zl, 20, false, 32);                 // zl f32
  attn_f<<<1024, 256, 0, stream>>>(zl, gamma, ztp, out + OFF_ZT);

  // --- AE decoder ---
  u16* d1 = h3; u16* d2 = h2; u16* d3 = h1;
  MG(2, false, false, 1, true, ztp, 32, Wd1t, 32, d1, 512, 8192, 512, 32, 32, bd1);
  MG(2, false, false, 1, true, d1, 512, Wd2t, 512, d2, 256, 8192, 256, 512, 512, bd2);
  MGS(2, false, true, d2, 256, Wd3t, 256, d3, 8192, 128, 256, 4, 64, 128, bd3);
  MG(1, false, false, 1, false, d3, 128, Wxt, 128, out + OFF_XHAT, 2000,
     8192, 2000, 128, 128, bx);

  // --- SGAE decoder: z_hat = (adj@(adj@((adj@zt)@(Wg4@Wg5))))@Wg6 ---
  ADJS(ztp, 32, aztp, 32, true, 32);
  u16* Wg5t = trB;   // trB free until next ADJS; Wg5t [128,256] fits easily
  TR32(Wg5, 256, 128, 128, Wg5t, 256, 256);
  MG(0, true, false, 1, false, Wg4, 256, Wg5t, 256, W45, 128, 20, 128, 256, 256, nullptr);
  TR32(W45, 20, 128, 128, W45t, 32, 32);
  u16* u = tA; u16* v = tB;
  MG(0, false, false, 1, true, aztp, 32, W45t, 32, u, 128, 8192, 128, 32, 32, nullptr);
  ADJS(u, 128, v, 128, true, 128);
  ADJS(v, 128, av, 128, true, 128);
  MG(0, false, false, 1, false, av, 128, Wg6t, 128, out + OFF_ZHAT, 2000,
     8192, 2000, 128, 128, nullptr);
  padzhb_k<<<8192, 256, 0, stream>>>(out + OFF_ZHAT, zhb);

  // --- adj_hat = sigmoid(zsg gram) + sigmoid(zhat gram), fused symmetric ---
  gram2<false><<<dim3(64, 64), 256, 0, stream>>>(zsgb, 32, 32, zhb, 2016, 2016,
                                                 out + OFF_ADJ, 8192, 8192);

  // --- soft assignments ---
  softassign_k<true><<<32, 256, 0, stream>>>(ztp, 32, cl, out + OFF_Q);
  softassign_k<false><<<32, 256, 0, stream>>>(zae, 20, cl, out + OFF_Q1);
  softassign_k<false><<<32, 256, 0, stream>>>(zsg, 20, cl, out + OFF_Q2);

  st_probe<<<1, 64, 0, stream>>>(out, sfl);

  #undef GD
  #undef MG
  #undef MGS
  #undef ADJS
  #undef TR32
  #undef TRB
}

// Round 9
// 1148.399 us; speedup vs baseline: 1.3489x; 1.0366x over previous
//
#include <hip/hip_runtime.h>
#include <stdint.h>

typedef unsigned short u16;
typedef short short8 __attribute__((ext_vector_type(8)));
typedef float f32x4 __attribute__((ext_vector_type(4)));
typedef __bf16 bf16x8 __attribute__((ext_vector_type(8)));

#define DEV static __device__ __forceinline__

DEV float bf2f(u16 h) {
  union { unsigned u; float f; } v; v.u = ((unsigned)h) << 16; return v.f;
}
DEV u16 f2bf(float f) {
  union { float f; unsigned u; } v; v.f = f;
  return (u16)((v.u + 0x7fffu + ((v.u >> 16) & 1u)) >> 16);  // RNE
}

// ---------------------------------------------------------------------------
// Transpose to bf16 [C, Kpad]: dst[c][r] = cvt(src[r][c]) for r<R, else 0.
// Turns every GEMM B-operand into the vectorized [N,K] short8 path.
// grid: (ceil(Kpad/64), ceil(C/64)), block 256. Kpad, ldd multiples of 8.
// ---------------------------------------------------------------------------
template<bool F32>
__global__ void tr_k(const void* __restrict__ src, int R, int C, int lds,
                     u16* __restrict__ dst, int ldd, int Kpad)
{
  __shared__ u16 tile[64][72];
  const int t = threadIdx.x;
  const int r0 = blockIdx.x << 6, c0 = blockIdx.y << 6;
  const int sr = t >> 2, sc = (t & 3) << 4;
  #pragma unroll
  for (int j = 0; j < 16; ++j) {
    const int r = r0 + sr, c = c0 + sc + j;
    u16 v = 0;
    if (r < R && c < C)
      v = F32 ? f2bf(((const float*)src)[(size_t)r * lds + c])
              : ((const u16*)src)[(size_t)r * lds + c];
    tile[sr][sc + j] = v;
  }
  __syncthreads();
  const int dc = t >> 2, dr = (t & 3) << 4;
  const int gc = c0 + dc;
  if (gc < C) {
    #pragma unroll
    for (int h = 0; h < 2; ++h) {
      const int gr = r0 + dr + (h << 3);
      if (gr < Kpad) {                 // gr, Kpad both mult of 8
        short8 o;
        #pragma unroll
        for (int j = 0; j < 8; ++j) o[j] = (short)tile[dr + (h << 3) + j][dc];
        *(short8*)&dst[(size_t)gc * ldd + gr] = o;
      }
    }
  }
}

// ---------------------------------------------------------------------------
// MFMA GEMM: C[M,N] = act(A @ B + bias), f32 accumulate, software-pipelined
// staging. A row-major [M,K] f32/bf16; B: LB=0 [K,N] (legacy) / LB=1 [N,K].
// MODE: 0 plain,1 +bias,2 lrelu,3 sigmoid. OUTBF: bf16 C.
// ---------------------------------------------------------------------------
template<int MODE, bool AF32, bool BF32, int LB, bool OUTBF>
__global__ __launch_bounds__(256, 2) void mg(
    const void* __restrict__ Av, int lda,
    const void* __restrict__ Bv, int ldb,
    void* __restrict__ Cv, int ldc,
    int M, int N, int K, int Kreal,
    const float* __restrict__ bias)
{
  __shared__ u16 As[128 * 40];
  __shared__ u16 Bs[128 * 40];
  const int t = threadIdx.x;
  const int w = t >> 6, l = t & 63;
  const int l15 = l & 15, lhi = l >> 4;
  const int bm = blockIdx.y << 7, bn = blockIdx.x << 7;
  const int wm = (w >> 1) << 6, wn = (w & 1) << 6;
  const int srow = t >> 2, scol = (t & 3) << 3;
  const int bcol = t & 127, bkh = (t >> 7) << 4;

  f32x4 acc[4][4] = {};
  short8 pa[2], pb[2];

  auto LDA_ = [&](int kt) {
    #pragma unroll
    for (int c = 0; c < 2; ++c) {
      const int gc = kt + scol;
      short8 v = {};
      const int ga = bm + srow + (c << 6);
      if ((gc + 8 <= K) && ga < M) {
        if (AF32) {
          const float* p = (const float*)Av + (size_t)ga * lda + gc;
          #pragma unroll
          for (int j = 0; j < 8; ++j) v[j] = (short)f2bf(p[j]);
        } else {
          v = *(const short8*)((const u16*)Av + (size_t)ga * lda + gc);
        }
      }
      pa[c] = v;
    }
  };
  auto LDB_ = [&](int kt) {
    if (LB == 1) {
      #pragma unroll
      for (int c = 0; c < 2; ++c) {
        const int gc = kt + scol;
        short8 v = {};
        const int gn = bn + srow + (c << 6);
        if ((gc + 8 <= K) && gn < N) {
          if (BF32) {
            const float* p = (const float*)Bv + (size_t)gn * ldb + gc;
            #pragma unroll
            for (int j = 0; j < 8; ++j) v[j] = (short)f2bf(p[j]);
          } else {
            v = *(const short8*)((const u16*)Bv + (size_t)gn * ldb + gc);
          }
        }
        pb[c] = v;
      }
    } else {
      #pragma unroll
      for (int h = 0; h < 2; ++h) {
        const int k0 = bkh + (h << 3);
        short8 v = {};
        const int gn = bn + bcol;
        if (gn < N) {
          #pragma unroll
          for (int j = 0; j < 8; ++j) {
            const int gk = kt + k0 + j;
            if (gk < Kreal) {
              if (BF32) v[j] = (short)f2bf(((const float*)Bv)[(size_t)gk * ldb + gn]);
              else      v[j] = (short)((const u16*)Bv)[(size_t)gk * ldb + gn];
            }
          }
        }
        pb[h] = v;
      }
    }
  };

  LDA_(0); LDB_(0);
  for (int kt = 0; kt < K; kt += 32) {
    #pragma unroll
    for (int c = 0; c < 2; ++c)
      *(short8*)&As[(srow + (c << 6)) * 40 + scol] = pa[c];
    if (LB == 1) {
      #pragma unroll
      for (int c = 0; c < 2; ++c)
        *(short8*)&Bs[(srow + (c << 6)) * 40 + scol] = pb[c];
    } else {
      #pragma unroll
      for (int h = 0; h < 2; ++h)
        *(short8*)&Bs[bcol * 40 + bkh + (h << 3)] = pb[h];
    }
    __syncthreads();
    if (kt + 32 < K) { LDA_(kt + 32); LDB_(kt + 32); }
    short8 af[4], bfr[4];
    #pragma unroll
    for (int m = 0; m < 4; ++m)
      af[m] = *(const short8*)&As[(wm + (m << 4) + l15) * 40 + (lhi << 3)];
    #pragma unroll
    for (int n = 0; n < 4; ++n)
      bfr[n] = *(const short8*)&Bs[(wn + (n << 4) + l15) * 40 + (lhi << 3)];
    #pragma unroll
    for (int m = 0; m < 4; ++m) {
      #pragma unroll
      for (int n = 0; n < 4; ++n)
        acc[m][n] = __builtin_amdgcn_mfma_f32_16x16x32_bf16(
            __builtin_bit_cast(bf16x8, af[m]),
            __builtin_bit_cast(bf16x8, bfr[n]), acc[m][n], 0, 0, 0);
    }
    __syncthreads();
  }

  #pragma unroll
  for (int m = 0; m < 4; ++m) {
    #pragma unroll
    for (int n = 0; n < 4; ++n) {
      #pragma unroll
      for (int r = 0; r < 4; ++r) {
        const int row = bm + wm + (m << 4) + (lhi << 2) + r;
        const int col = bn + wn + (n << 4) + l15;
        if (row < M && col < N) {
          const float v0 = acc[m][n][r];
          float o;
          if (MODE == 0) o = v0;
          else if (MODE == 1) o = v0 + bias[col];
          else if (MODE == 2) { const float s = v0 + bias[col]; o = (s > 0.f) ? s : 0.2f * s; }
          else o = 1.f / (1.f + __expf(-v0));
          if (OUTBF) ((u16*)Cv)[(size_t)row * ldc + col] = f2bf(o);
          else       ((float*)Cv)[(size_t)row * ldc + col] = o;
        }
      }
    }
  }
}

// ---------------------------------------------------------------------------
// Split-K MFMA GEMM (narrow N<=128). B is ALWAYS bf16 B^T [N,K] (vectorized
// short8 loads — the scalar column-gather path is gone).
// Grid (1, M/128, KS); partials P[z][row][0..PN).
// ---------------------------------------------------------------------------
template<bool AF32>
__global__ __launch_bounds__(256, 2) void mgs(
    const void* __restrict__ Av, int lda,
    const u16* __restrict__ Bt, int ldb,
    float* __restrict__ P,
    int M, int N, int K, int KSZ, int PN)
{
  __shared__ u16 As[128 * 40];
  __shared__ u16 Bs[128 * 40];
  const int t = threadIdx.x;
  const int w = t >> 6, l = t & 63;
  const int l15 = l & 15, lhi = l >> 4;
  const int bm = blockIdx.y << 7;
  const int wm = (w >> 1) << 6, wn = (w & 1) << 6;
  const int srow = t >> 2, scol = (t & 3) << 3;
  const int kbeg = blockIdx.z * KSZ;
  const int kend = min(K, kbeg + KSZ);

  f32x4 acc[4][4] = {};
  short8 pa[2], pb[2];

  auto LDA_ = [&](int kt) {
    #pragma unroll
    for (int c = 0; c < 2; ++c) {
      const int gc = kt + scol;
      short8 v = {};
      const int ga = bm + srow + (c << 6);
      if ((gc + 8 <= K) && ga < M) {
        if (AF32) {
          const float* p = (const float*)Av + (size_t)ga * lda + gc;
          #pragma unroll
          for (int j = 0; j < 8; ++j) v[j] = (short)f2bf(p[j]);
        } else {
          v = *(const short8*)((const u16*)Av + (size_t)ga * lda + gc);
        }
      }
      pa[c] = v;
    }
  };
  auto LDB_ = [&](int kt) {
    #pragma unroll
    for (int c = 0; c < 2; ++c) {
      const int gc = kt + scol;
      short8 v = {};
      const int gn = srow + (c << 6);
      if ((gc + 8 <= K) && gn < N)
        v = *(const short8*)(Bt + (size_t)gn * ldb + gc);
      pb[c] = v;
    }
  };

  LDA_(kbeg); LDB_(kbeg);
  for (int kt = kbeg; kt < kend; kt += 32) {
    #pragma unroll
    for (int c = 0; c < 2; ++c)
      *(short8*)&As[(srow + (c << 6)) * 40 + scol] = pa[c];
    #pragma unroll
    for (int c = 0; c < 2; ++c)
      *(short8*)&Bs[(srow + (c << 6)) * 40 + scol] = pb[c];
    __syncthreads();
    if (kt + 32 < kend) { LDA_(kt + 32); LDB_(kt + 32); }
    short8 af[4], bfr[4];
    #pragma unroll
    for (int m = 0; m < 4; ++m)
      af[m] = *(const short8*)&As[(wm + (m << 4) + l15) * 40 + (lhi << 3)];
    #pragma unroll
    for (int n = 0; n < 4; ++n)
      bfr[n] = *(const short8*)&Bs[(wn + (n << 4) + l15) * 40 + (lhi << 3)];
    #pragma unroll
    for (int m = 0; m < 4; ++m) {
      #pragma unroll
      for (int n = 0; n < 4; ++n)
        acc[m][n] = __builtin_amdgcn_mfma_f32_16x16x32_bf16(
            __builtin_bit_cast(bf16x8, af[m]),
            __builtin_bit_cast(bf16x8, bfr[n]), acc[m][n], 0, 0, 0);
    }
    __syncthreads();
  }

  float* Pz = P + (size_t)blockIdx.z * M * PN;
  #pragma unroll
  for (int m = 0; m < 4; ++m) {
    #pragma unroll
    for (int n = 0; n < 4; ++n) {
      const int col = wn + (n << 4) + l15;
      if (col < PN) {
        #pragma unroll
        for (int r = 0; r < 4; ++r) {
          const int row = bm + wm + (m << 4) + (lhi << 2) + r;
          Pz[(size_t)row * PN + col] = acc[m][n][r];
        }
      }
    }
  }
}

template<int MODE, bool OUTBF>
__global__ void redk(const float* __restrict__ P, int KS, int PN,
                     void* __restrict__ Cv, int M, int N,
                     const float* __restrict__ bias)
{
  const int i = blockIdx.x * 256 + threadIdx.x;
  if (i >= M * N) return;
  const int row = i / N, col = i - row * N;
  float s = 0.f;
  for (int z = 0; z < KS; ++z) s += P[((size_t)z * M + row) * PN + col];
  float o;
  if (MODE == 0) o = s;
  else if (MODE == 1) o = s + bias[col];
  else { const float b = s + bias[col]; o = (b > 0.f) ? b : 0.2f * b; }
  if (OUTBF) ((u16*)Cv)[i] = f2bf(o);
  else       ((float*)Cv)[i] = o;
}

// ---------------------------------------------------------------------------
// Fused symmetric dual gram — EXACT r4 structure (best measured: 330us).
// Reg-staged LDS, stride-40 rows, 1-step reg prefetch, 2 barriers/step,
// identity block mapping, __launch_bounds__(256,2), VGPR 96.
// r5 (2-deep prefetch), r6 (XCD swizzle), r7 (occupancy bound) all regressed
// — this is a sharp local optimum; do not touch the K-loop.
// ---------------------------------------------------------------------------
template<bool TEST>
__global__ __launch_bounds__(256, 2) void gram2(
    const u16* __restrict__ Z1, int ld1, int K1,
    const u16* __restrict__ Z2, int ld2, int K2,
    float* __restrict__ C, int ldc, int M)
{
  __shared__ union SM {
    u16 stage[2][128 * 40];
    float tb[32][132];
  } sm;
  const int bx = blockIdx.x, by = blockIdx.y;
  if (bx < by) return;
  u16* As = sm.stage[0];
  u16* Bs = sm.stage[1];
  const int t = threadIdx.x;
  const int w = t >> 6, l = t & 63;
  const int l15 = l & 15, lhi = l >> 4;
  const int bm = by << 7, bn = bx << 7;
  const int wm = (w >> 1) << 6, wn = (w & 1) << 6;
  const int srow = t >> 2, scol = (t & 3) << 3;

  f32x4 acc1[4][4] = {};
  f32x4 acc2[4][4] = {};
  short8 va0, va1, vb0, vb1;

  auto LOD = [&](const u16* Z, int ld, int KK, int kt) {
    short8 a0 = {}, a1 = {}, b0 = {}, b1 = {};
    const int gc = kt + scol;
    if (gc + 8 <= KK) {
      a0 = *(const short8*)(Z + (size_t)(bm + srow) * ld + gc);
      a1 = *(const short8*)(Z + (size_t)(bm + srow + 64) * ld + gc);
      b0 = *(const short8*)(Z + (size_t)(bn + srow) * ld + gc);
      b1 = *(const short8*)(Z + (size_t)(bn + srow + 64) * ld + gc);
    }
    va0 = a0; va1 = a1; vb0 = b0; vb1 = b1;
  };
  auto STORE = [&]() {
    *(short8*)&As[srow * 40 + scol] = va0;
    *(short8*)&As[(srow + 64) * 40 + scol] = va1;
    *(short8*)&Bs[srow * 40 + scol] = vb0;
    *(short8*)&Bs[(srow + 64) * 40 + scol] = vb1;
  };
  auto FMM = [&](f32x4 (&ACC)[4][4]) {
    short8 af[4], bfr[4];
    #pragma unroll
    for (int m = 0; m < 4; ++m)
      af[m] = *(const short8*)&As[(wm + (m << 4) + l15) * 40 + (lhi << 3)];
    #pragma unroll
    for (int n = 0; n < 4; ++n)
      bfr[n] = *(const short8*)&Bs[(wn + (n << 4) + l15) * 40 + (lhi << 3)];
    #pragma unroll
    for (int m = 0; m < 4; ++m) {
      #pragma unroll
      for (int n = 0; n < 4; ++n)
        ACC[m][n] = __builtin_amdgcn_mfma_f32_16x16x32_bf16(
            __builtin_bit_cast(bf16x8, af[m]),
            __builtin_bit_cast(bf16x8, bfr[n]), ACC[m][n], 0, 0, 0);
    }
  };

  LOD(Z1, ld1, K1, 0);
  for (int kt = 0; kt < K1; kt += 32) {
    STORE();
    __syncthreads();
    if (kt + 32 < K1) LOD(Z1, ld1, K1, kt + 32);
    else LOD(Z2, ld2, K2, 0);
    FMM(acc1);
    __syncthreads();
  }
  for (int kt = 0; kt < K2; kt += 32) {
    STORE();
    __syncthreads();
    if (kt + 32 < K2) LOD(Z2, ld2, K2, kt + 32);
    FMM(acc2);
    __syncthreads();
  }

  auto cval = [&](int m, int n, int r) -> float {
    const float a1 = acc1[m][n][r], a2 = acc2[m][n][r];
    if (TEST) return a1 + a2;
    return 1.f / (1.f + __expf(-a1)) + 1.f / (1.f + __expf(-a2));
  };

  #pragma unroll
  for (int m = 0; m < 4; ++m) {
    #pragma unroll
    for (int n = 0; n < 4; ++n) {
      #pragma unroll
      for (int r = 0; r < 4; ++r) {
        const int row = bm + wm + (m << 4) + (lhi << 2) + r;
        const int col = bn + wn + (n << 4) + l15;
        C[(size_t)row * ldc + col] = cval(m, n, r);
      }
    }
  }

  if (bx != by) {
    #pragma unroll
    for (int p = 0; p < 4; ++p) {
      __syncthreads();
      if (wn == ((p & 2) << 5)) {
        #pragma unroll
        for (int n2 = 0; n2 < 2; ++n2) {
          const int n = ((p & 1) << 1) + n2;
          #pragma unroll
          for (int m = 0; m < 4; ++m)
            #pragma unroll
            for (int r = 0; r < 4; ++r)
              sm.tb[(n2 << 4) + l15][wm + (m << 4) + (lhi << 2) + r] = cval(m, n, r);
        }
      }
      __syncthreads();
      #pragma unroll
      for (int i = 0; i < 16; ++i) {
        const int e = t + (i << 8);
        const int rr = e >> 7, cc = e & 127;
        C[(size_t)(bn + (p << 5) + rr) * ldc + bm + cc] = sm.tb[rr][cc];
      }
    }
  }
}

// --------------------------- small kernels ---------------------------------
__global__ void zi_k(const float* __restrict__ a, const float* __restrict__ zae,
                     const float* __restrict__ zsg, u16* __restrict__ zi)
{
  const int i = blockIdx.x * 256 + threadIdx.x;
  if (i < 163840) {
    const float av = a[i];
    zi[i] = f2bf(av * zae[i] + (1.f - av) * zsg[i]);
  }
}

__global__ void copyf_k(const float* __restrict__ src, float* __restrict__ dst, int n)
{
  const int i = blockIdx.x * 256 + threadIdx.x;
  if (i < n) dst[i] = src[i];
}

__global__ void f2bf4_k(const float* __restrict__ s, u16* __restrict__ d, long n4)
{
  long i = (long)blockIdx.x * 256 + threadIdx.x;
  const long stride = (long)gridDim.x * 256;
  for (; i < n4; i += stride) {
    const float4 v = ((const float4*)s)[i];
    union { u16 h[4]; unsigned long long u; } o;
    o.h[0] = f2bf(v.x); o.h[1] = f2bf(v.y); o.h[2] = f2bf(v.z); o.h[3] = f2bf(v.w);
    ((unsigned long long*)d)[i] = o.u;
  }
}

// 8192 x 2000 f32 -> 8192 x 2016 bf16, zero pad cols [2000,2016).
__global__ void padzhb_k(const float* __restrict__ s, u16* __restrict__ d)
{
  const int row = blockIdx.x;
  for (int g = threadIdx.x; g < 504; g += 256) {
    const int c4 = g << 2;
    union { u16 h[4]; unsigned long long u; } o;
    if (c4 < 2000) {
      const float4 v = *(const float4*)(s + (size_t)row * 2000 + c4);
      o.h[0] = f2bf(v.x); o.h[1] = f2bf(v.y); o.h[2] = f2bf(v.z); o.h[3] = f2bf(v.w);
    } else {
      o.u = 0ULL;
    }
    *(unsigned long long*)(d + (size_t)row * 2016 + c4) = o.u;
  }
}

__global__ void padbf_k(const float* __restrict__ s, u16* __restrict__ d)
{
  const int i = blockIdx.x * 256 + threadIdx.x;
  const int row = i >> 5, col = i & 31;
  d[i] = (col < 20) ? f2bf(s[row * 20 + col]) : (u16)0;
}

__global__ __launch_bounds__(256) void attn_f(const float* __restrict__ zl,
                                              const float* __restrict__ gammap,
                                              u16* __restrict__ ztp,
                                              float* __restrict__ ztout)
{
  __shared__ float tile[256 * 20];
  const int t = threadIdx.x;
  const int sub = t & 31;
  const int row = blockIdx.x * 8 + (t >> 5);
  float qv[20];
  #pragma unroll
  for (int k = 0; k < 20; ++k) qv[k] = zl[(size_t)row * 20 + k];
  float m = -1e30f, ssum = 0.f;
  float acc[20] = {};
  for (int j0 = 0; j0 < 8192; j0 += 256) {
    #pragma unroll
    for (int k = 0; k < 20; ++k) tile[t * 20 + k] = zl[(size_t)(j0 + t) * 20 + k];
    __syncthreads();
    for (int jj = 0; jj < 8; ++jj) {
      const int jl = (jj << 5) + sub;
      float s = 0.f;
      #pragma unroll
      for (int k = 0; k < 20; ++k) s += qv[k] * tile[jl * 20 + k];
      if (s > m) {
        const float sc = __expf(m - s);
        ssum *= sc;
        #pragma unroll
        for (int k = 0; k < 20; ++k) acc[k] *= sc;
        m = s;
      }
      const float p = __expf(s - m);
      ssum += p;
      #pragma unroll
      for (int k = 0; k < 20; ++k) acc[k] += p * tile[jl * 20 + k];
    }
    __syncthreads();
  }
  #pragma unroll
  for (int off = 16; off >= 1; off >>= 1) {
    const float mo = __shfl_xor(m, off, 32);
    const float so = __shfl_xor(ssum, off, 32);
    const float nm = fmaxf(m, mo);
    const float e1 = __expf(m - nm), e2 = __expf(mo - nm);
    ssum = ssum * e1 + so * e2;
    #pragma unroll
    for (int k = 0; k < 20; ++k) {
      const float ao = __shfl_xor(acc[k], off, 32);
      acc[k] = acc[k] * e1 + ao * e2;
    }
    m = nm;
  }
  if (sub == 0) {
    const float g = gammap[0];
    #pragma unroll
    for (int k = 0; k < 20; ++k) {
      const float v = g * (acc[k] / ssum) + qv[k];
      ztout[(size_t)row * 20 + k] = v;
      ztp[(size_t)row * 32 + k] = f2bf(v);
    }
    #pragma unroll
    for (int k = 20; k < 32; ++k) ztp[(size_t)row * 32 + k] = 0;
  }
}

template<bool BFIN>
__global__ void softassign_k(const void* __restrict__ zp, int stride,
                             const float* __restrict__ cl, float* __restrict__ outq)
{
  const int i = blockIdx.x * 256 + threadIdx.x;
  float zv[20];
  #pragma unroll
  for (int k = 0; k < 20; ++k)
    zv[k] = BFIN ? bf2f(((const u16*)zp)[(size_t)i * stride + k])
                 : ((const float*)zp)[(size_t)i * stride + k];
  float qv[10], s = 0.f;
  #pragma unroll
  for (int j = 0; j < 10; ++j) {
    float d2 = 0.f;
    #pragma unroll
    for (int k = 0; k < 20; ++k) { const float d = zv[k] - cl[j * 20 + k]; d2 += d * d; }
    qv[j] = 1.f / (1.f + d2);
    s += qv[j];
  }
  const float inv = 1.f / s;
  #pragma unroll
  for (int j = 0; j < 10; ++j) outq[(size_t)i * 10 + j] = qv[j] * inv;
}

// --------------------------- self-test -------------------------------------
DEV float stA(int i, int k) { return (float)(((i * 5 + k * 7) % 3) - 1); }
DEV float stB(int j, int k) { return (float)(((j * 11 + k * 13) % 5) - 2); }

__global__ void st_setup(u16* At, float* Atf, u16* Bnk, float* Bknf, u16* Bknb, int* fl)
{
  const int idx = blockIdx.x * 256 + threadIdx.x;
  { const int i = idx >> 6, k = idx & 63;
    At[idx] = f2bf(stA(i, k)); Atf[idx] = stA(i, k);
    Bnk[idx] = f2bf(stB(i, k)); }
  { const int k = idx >> 7, j = idx & 127;
    Bknf[idx] = stB(j, k); Bknb[idx] = f2bf(stB(j, k)); }
  if (idx == 0) *fl = 0;
}

__global__ void st_check(const float* C, int bit, int* fl)
{
  const int i = blockIdx.x, j = threadIdx.x;
  float ref = 0.f;
  for (int k = 0; k < 64; ++k) ref += stA(i, k) * stB(j, k);
  if (C[i * 128 + j] != ref) atomicOr(fl, bit);
}

__global__ void st2_setup(u16* Z1, u16* Z2)
{
  const int idx = blockIdx.x * 256 + threadIdx.x;
  if (idx < 8192)  { const int i = idx >> 5, k = idx & 31; Z1[idx] = f2bf(stA(i, k)); }
  if (idx < 16384) { const int i = idx >> 6, k = idx & 63; Z2[idx] = f2bf(stB(i, k)); }
}

__global__ void st2_check(const float* C, int* fl)
{
  const int i = blockIdx.x, j = threadIdx.x;
  float ref = 0.f;
  for (int k = 0; k < 32; ++k) ref += stA(i, k) * stA(j, k);
  for (int k = 0; k < 64; ++k) ref += stB(i, k) * stB(j, k);
  if (C[i * 256 + j] != ref) atomicOr(fl, 16);
}

__global__ void st_probe(float* out0, const int* fl)
{
  if (threadIdx.x == 0 && blockIdx.x == 0 && *fl) *out0 = 4096.f + (float)(*fl);
}

// ---------------------------------------------------------------------------
extern "C" void kernel_launch(void* const* d_in, const int* in_sizes, int n_in,
                              void* d_out, int out_size, void* d_ws, size_t ws_size,
                              hipStream_t stream)
{
  (void)in_sizes; (void)n_in; (void)out_size;
  const float* x     = (const float*)d_in[0];
  const float* adj   = (const float*)d_in[1];
  const float* a     = (const float*)d_in[2];
  const float* cl    = (const float*)d_in[3];
  const float* gamma = (const float*)d_in[4];
  const float* We1 = (const float*)d_in[5];  const float* be1 = (const float*)d_in[6];
  const float* We2 = (const float*)d_in[7];  const float* be2 = (const float*)d_in[8];
  const float* We3 = (const float*)d_in[9];  const float* be3 = (const float*)d_in[10];
  const float* Wz  = (const float*)d_in[11]; const float* bz  = (const float*)d_in[12];
  const float* Wd1 = (const float*)d_in[13]; const float* bd1 = (const float*)d_in[14];
  const float* Wd2 = (const float*)d_in[15]; const float* bd2 = (const float*)d_in[16];
  const float* Wd3 = (const float*)d_in[17]; const float* bd3 = (const float*)d_in[18];
  const float* Wx  = (const float*)d_in[19]; const float* bx  = (const float*)d_in[20];
  const float* Wg1 = (const float*)d_in[21];
  const float* Wg2 = (const float*)d_in[22];
  const float* Wg3 = (const float*)d_in[23];
  const float* Wg4 = (const float*)d_in[24];
  const float* Wg5 = (const float*)d_in[25];
  const float* Wg6 = (const float*)d_in[26];
  float* out = (float*)d_out;

  const size_t OFF_XHAT = 0;
  const size_t OFF_ZHAT = 16384000;
  const size_t OFF_ADJ  = 32768000;
  const size_t OFF_ZAE  = 99876864;
  const size_t OFF_ZSG  = 100040704;
  const size_t OFF_Q    = 100204544;
  const size_t OFF_Q1   = 100286464;
  const size_t OFF_Q2   = 100368384;
  const size_t OFF_ZT   = 100450304;

  char* cur = (char*)d_ws;
  auto ab = [&](size_t bytes) {
    char* p = cur;
    cur += ((bytes + 255) & ~(size_t)255);
    return p;
  };
  u16*  h1   = (u16*)ab(8192 * 128 * 2);
  u16*  h2   = (u16*)ab(8192 * 256 * 2);
  u16*  h3   = (u16*)ab(8192 * 512 * 2);
  u16*  tA   = (u16*)ab(8192 * 128 * 2);
  u16*  tB   = (u16*)ab(8192 * 128 * 2);
  u16*  tC   = (u16*)ab(8192 * 256 * 2);
  u16*  av   = (u16*)ab(8192 * 128 * 2);
  u16*  t3   = (u16*)ab(8192 * 20 * 2);
  float* zae = (float*)ab(8192 * 20 * 4);
  float* zsg = (float*)ab(8192 * 20 * 4);
  u16*  zsgb = (u16*)ab(8192 * 32 * 2);
  u16*  zib  = (u16*)ab(8192 * 20 * 2);
  float* zl  = (float*)ab(8192 * 20 * 4);
  u16*  ztp  = (u16*)ab(8192 * 32 * 2);
  u16*  aztp = (u16*)ab(8192 * 32 * 2);
  float* W45 = (float*)ab(20 * 128 * 4);
  u16*  zhb  = (u16*)ab((size_t)8192 * 2016 * 2);
  u16*  xb   = (u16*)ab((size_t)8192 * 2000 * 2);
  // transposed-B operands (bf16 [N,K])
  u16*  trB  = (u16*)ab((size_t)128 * 8192 * 2);   // reused for ADJS B's + Wg5t
  u16*  We1t = (u16*)ab(128 * 2016 * 2);
  u16*  We2t = (u16*)ab(256 * 128 * 2);
  u16*  We3t = (u16*)ab(512 * 256 * 2);
  u16*  Wzt  = (u16*)ab(32 * 512 * 2);
  u16*  Wd1t = (u16*)ab(512 * 32 * 2);
  u16*  Wd2t = (u16*)ab(256 * 512 * 2);
  u16*  Wd3t = (u16*)ab(128 * 256 * 2);
  u16*  Wxt  = (u16*)ab(2000 * 128 * 2);
  u16*  Wg2t = (u16*)ab(256 * 128 * 2);
  u16*  Wg3t = (u16*)ab(32 * 256 * 2);
  u16*  Wg6t = (u16*)ab(2000 * 128 * 2);
  u16*  W123t = (u16*)ab(32 * 2016 * 2);   // (Wg1@Wg2@Wg3)^T, K zero-padded
  u16*  W456t = (u16*)ab(2000 * 32 * 2);   // (W45@Wg6)^T,    K zero-padded
  u16*  sAt  = (u16*)ab(8192 * 2);
  float* sAtf = (float*)ab(8192 * 4);
  u16*  sBnk = (u16*)ab(8192 * 2);
  float* sBknf = (float*)ab(8192 * 4);
  u16*  sBknb = (u16*)ab(8192 * 2);
  u16*  sBt32 = (u16*)ab(128 * 64 * 2);
  u16*  sBtb  = (u16*)ab(128 * 64 * 2);
  float* sCt = (float*)ab(128 * 128 * 4);
  u16*  sZ1  = (u16*)ab(256 * 32 * 2);
  u16*  sZ2  = (u16*)ab(256 * 64 * 2);
  float* sCt2 = (float*)ab(256 * 256 * 4);
  int*  sfl  = (int*)ab(256);

  const size_t fixedB = (size_t)(cur - (char*)d_ws);
  const size_t P16B = (size_t)16 * 8192 * 128 * 4;
  const size_t P8B  = (size_t)8 * 8192 * 128 * 4;
  const size_t ADJB = (size_t)8192 * 8192 * 2;
  const bool kbig = (fixedB + P16B + ADJB) <= ws_size;
  float* P = (float*)ab(kbig ? P16B : P8B);
  u16* adjb = (u16*)cur;
  const bool use_adjb = ((size_t)(cur - (char*)d_ws) + ADJB) <= ws_size;
  // KS=8 everywhere (r8 win): halves split-K partial traffic at identical
  // residency (512 blocks = 2/CU exactly).
  const int KS_ADJ = 8;
  const int KSZ_ADJ = 1024;
  const int KS_2K = 8;
  const int KSZ_2K = 256;

  #define GD(N, M) dim3(((N) + 127) / 128, ((M) + 127) / 128)
  #define MG(MODE, AF, BF, LB, OB, A, LDA, B, LDB, C, LDC, M, N, K, KR, BIAS) \
    mg<MODE, AF, BF, LB, OB><<<GD(N, M), 256, 0, stream>>>( \
        A, LDA, B, LDB, C, LDC, M, N, K, KR, BIAS)
  #define MGS(RMODE, AF, OB, A, LDA, BT, LDB, C, M, N, K, KS, KSZ, PN, BIAS) do { \
    mgs<AF><<<dim3(1, (M) / 128, KS), 256, 0, stream>>>( \
        A, LDA, BT, LDB, P, M, N, K, KSZ, PN); \
    redk<RMODE, OB><<<(((M) * (N)) + 255) / 256, 256, 0, stream>>>( \
        P, KS, PN, C, M, N, BIAS); \
  } while (0)
  #define TR32(S, R, C, LD, D, LDD, KP) \
    tr_k<true><<<dim3(((KP) + 63) / 64, ((C) + 63) / 64), 256, 0, stream>>>( \
        S, R, C, LD, D, LDD, KP)
  #define TRB(S, R, C, LD, D, LDD, KP) \
    tr_k<false><<<dim3(((KP) + 63) / 64, ((C) + 63) / 64), 256, 0, stream>>>( \
        S, R, C, LD, D, LDD, KP)

  // --- self-tests (exact integer arithmetic; sentinel on failure) ---
  st_setup<<<32, 256, 0, stream>>>(sAt, sAtf, sBnk, sBknf, sBknb, sfl);
  MG(0, false, false, 1, false, sAt, 64, sBnk, 64, sCt, 128, 128, 128, 64, 64, nullptr);
  st_check<<<128, 128, 0, stream>>>(sCt, 1, sfl);
  TR32(sBknf, 64, 128, 128, sBt32, 64, 64);
  MG(0, true, false, 1, false, sAtf, 64, sBt32, 64, sCt, 128, 128, 128, 64, 64, nullptr);
  st_check<<<128, 128, 0, stream>>>(sCt, 2, sfl);
  TRB(sBknb, 64, 128, 128, sBtb, 64, 64);
  MGS(0, false, false, sAt, 64, sBtb, 64, sCt, 128, 128, 64, 2, 32, 128, nullptr);
  st_check<<<128, 128, 0, stream>>>(sCt, 8, sfl);
  st2_setup<<<64, 256, 0, stream>>>(sZ1, sZ2);
  gram2<true><<<dim3(2, 2), 256, 0, stream>>>(sZ1, 32, 32, sZ2, 64, 64, sCt2, 256, 256);
  st2_check<<<256, 256, 0, stream>>>(sCt2, sfl);

  // --- one-time weight transposes (f32 [K,N] -> bf16 [N,Kpad]) ---
  TR32(We1, 2000, 128, 128, We1t, 2016, 2016);
  TR32(We2, 128, 256, 256, We2t, 128, 128);
  TR32(We3, 256, 512, 512, We3t, 256, 256);
  TR32(Wz,  512, 20,  20,  Wzt,  512, 512);
  TR32(Wd1, 20,  512, 512, Wd1t, 32,  32);
  TR32(Wd2, 512, 256, 256, Wd2t, 512, 512);
  TR32(Wd3, 256, 128, 128, Wd3t, 256, 256);
  TR32(Wx,  128, 2000, 2000, Wxt, 128, 128);
  TR32(Wg2, 128, 256, 256, Wg2t, 128, 128);
  TR32(Wg3, 256, 20,  20,  Wg3t, 256, 256);
  TR32(Wg6, 128, 2000, 2000, Wg6t, 128, 128);

  if (use_adjb)
    f2bf4_k<<<2048, 256, 0, stream>>>(adj, adjb, 16777216L);
  f2bf4_k<<<2048, 256, 0, stream>>>(x, xb, 4096000L);

  // ADJS: transpose the narrow activation to [N,8192] then split-K over adj
  #define ADJS(B, LDB, OUT, N, OB, PN) do { \
    TRB(B, 8192, N, LDB, trB, 8192, 8192); \
    if (use_adjb) MGS(0, false, OB, adjb, 8192, trB, 8192, OUT, 8192, N, 8192, KS_ADJ, KSZ_ADJ, PN, nullptr); \
    else          MGS(0, true,  OB, adj,  8192, trB, 8192, OUT, 8192, N, 8192, KS_ADJ, KSZ_ADJ, PN, nullptr); \
  } while (0)

  // --- AE encoder ---
  MGS(2, false, true, xb, 2000, We1t, 2016, h1, 8192, 128, 2000, KS_2K, KSZ_2K, 128, be1);
  MG(2, false, false, 1, true, h1, 128,  We2t, 128, h2, 256, 8192, 256, 128, 128, be2);
  MG(2, false, false, 1, true, h2, 256,  We3t, 256, h3, 512, 8192, 512, 256, 256, be3);
  MGS(1, false, false, h3, 512, Wzt, 512, zae, 8192, 20, 512, 4, 128, 32, bz);
  copyf_k<<<640, 256, 0, stream>>>(zae, out + OFF_ZAE, 163840);

  // --- SGAE encoder (reassociated): zsg = adj@adj@adj@(x@(Wg1@Wg2@Wg3)) ---
  // GNN layers have no activation, so the weight chain folds to W123
  // [2000,20]; all three adj-multiplies then run at N=20 (PN=32) instead of
  // two at N=128 — same adj traffic, 4x less partial/intermediate traffic.
  MG(0, true, false, 1, true, Wg1, 128, Wg2t, 128, tC, 256, 2000, 256, 128, 128, nullptr);
  MG(0, false, false, 1, true, tC, 256, Wg3t, 256, tA, 20, 2000, 20, 256, 256, nullptr);
  TRB(tA, 2000, 20, 20, W123t, 2016, 2016);
  MGS(0, false, true, xb, 2000, W123t, 2016, t3, 8192, 20, 2000, KS_2K, KSZ_2K, 32, nullptr);
  ADJS(t3, 20, tB, 20, true, 32);                   // adj @ (x@W123)
  ADJS(tB, 20, t3, 20, true, 32);                   // adj @ ...
  ADJS(t3, 20, zsg, 20, false, 32);                 // zsg f32
  copyf_k<<<640, 256, 0, stream>>>(zsg, out + OFF_ZSG, 163840);
  padbf_k<<<1024, 256, 0, stream>>>(zsg, zsgb);

  // --- fuse + attention ---
  zi_k<<<640, 256, 0, stream>>>(a, zae, zsg, zib);
  ADJS(zib, 20, zl, 20, false, 32);                 // zl f32
  attn_f<<<1024, 256, 0, stream>>>(zl, gamma, ztp, out + OFF_ZT);

  // --- AE decoder ---
  u16* d1 = h3; u16* d2 = h2; u16* d3 = h1;
  MG(2, false, false, 1, true, ztp, 32, Wd1t, 32, d1, 512, 8192, 512, 32, 32, bd1);
  MG(2, false, false, 1, true, d1, 512, Wd2t, 512, d2, 256, 8192, 256, 512, 512, bd2);
  MGS(2, false, true, d2, 256, Wd3t, 256, d3, 8192, 128, 256, 4, 64, 128, bd3);
  MG(1, false, false, 1, false, d3, 128, Wxt, 128, out + OFF_XHAT, 2000,
     8192, 2000, 128, 128, bx);

  // --- SGAE decoder (reassociated): z_hat = (adj@adj@adj@zt)@(Wg4@Wg5@Wg6) ---
  ADJS(ztp, 32, aztp, 32, true, 32);
  u16* Wg5t = trB;   // trB free until next ADJS; Wg5t [128,256] fits easily
  TR32(Wg5, 256, 128, 128, Wg5t, 256, 256);
  MG(0, true, false, 1, false, Wg4, 256, Wg5t, 256, W45, 128, 20, 128, 256, 256, nullptr);
  MG(0, true, false, 1, true, W45, 128, Wg6t, 128, tC, 2000, 20, 2000, 128, 128, nullptr);
  TRB(tC, 20, 2000, 2000, W456t, 32, 32);
  ADJS(aztp, 32, av, 32, true, 32);                 // adj @ (adj@zt)
  ADJS(av, 32, aztp, 32, true, 32);                 // adj @ ...
  MG(0, false, false, 1, false, aztp, 32, W456t, 32, out + OFF_ZHAT, 2000,
     8192, 2000, 32, 32, nullptr);
  padzhb_k<<<8192, 256, 0, stream>>>(out + OFF_ZHAT, zhb);

  // --- adj_hat = sigmoid(zsg gram) + sigmoid(zhat gram), fused symmetric ---
  gram2<false><<<dim3(64, 64), 256, 0, stream>>>(zsgb, 32, 32, zhb, 2016, 2016,
                                                 out + OFF_ADJ, 8192, 8192);

  // --- soft assignments ---
  softassign_k<true><<<32, 256, 0, stream>>>(ztp, 32, cl, out + OFF_Q);
  softassign_k<false><<<32, 256, 0, stream>>>(zae, 20, cl, out + OFF_Q1);
  softassign_k<false><<<32, 256, 0, stream>>>(zsg, 20, cl, out + OFF_Q2);

  st_probe<<<1, 64, 0, stream>>>(out, sfl);

  #undef GD
  #undef MG
  #undef MGS
  #undef ADJS
  #undef TR32
  #undef TRB
}

// Round 10
// 1143.529 us; speedup vs baseline: 1.3547x; 1.0043x over previous
//
#include <hip/hip_runtime.h>
#include <stdint.h>

typedef unsigned short u16;
typedef short short8 __attribute__((ext_vector_type(8)));
typedef float f32x4 __attribute__((ext_vector_type(4)));
typedef __bf16 bf16x8 __attribute__((ext_vector_type(8)));

#define DEV static __device__ __forceinline__

DEV float bf2f(u16 h) {
  union { unsigned u; float f; } v; v.u = ((unsigned)h) << 16; return v.f;
}
DEV u16 f2bf(float f) {
  union { float f; unsigned u; } v; v.f = f;
  return (u16)((v.u + 0x7fffu + ((v.u >> 16) & 1u)) >> 16);  // RNE
}

// ---------------------------------------------------------------------------
// Transpose to bf16 [C, Kpad]: dst[c][r] = cvt(src[r][c]) for r<R, else 0.
// grid: (ceil(Kpad/64), ceil(C/64)), block 256. Kpad, ldd multiples of 8.
// ---------------------------------------------------------------------------
template<bool F32>
__global__ void tr_k(const void* __restrict__ src, int R, int C, int lds,
                     u16* __restrict__ dst, int ldd, int Kpad)
{
  __shared__ u16 tile[64][72];
  const int t = threadIdx.x;
  const int r0 = blockIdx.x << 6, c0 = blockIdx.y << 6;
  const int sr = t >> 2, sc = (t & 3) << 4;
  #pragma unroll
  for (int j = 0; j < 16; ++j) {
    const int r = r0 + sr, c = c0 + sc + j;
    u16 v = 0;
    if (r < R && c < C)
      v = F32 ? f2bf(((const float*)src)[(size_t)r * lds + c])
              : ((const u16*)src)[(size_t)r * lds + c];
    tile[sr][sc + j] = v;
  }
  __syncthreads();
  const int dc = t >> 2, dr = (t & 3) << 4;
  const int gc = c0 + dc;
  if (gc < C) {
    #pragma unroll
    for (int h = 0; h < 2; ++h) {
      const int gr = r0 + dr + (h << 3);
      if (gr < Kpad) {                 // gr, Kpad both mult of 8
        short8 o;
        #pragma unroll
        for (int j = 0; j < 8; ++j) o[j] = (short)tile[dr + (h << 3) + j][dc];
        *(short8*)&dst[(size_t)gc * ldd + gr] = o;
      }
    }
  }
}

// ---------------------------------------------------------------------------
// MFMA GEMM: C[M,N] = act(A @ B + bias), f32 accumulate, software-pipelined
// staging. A row-major [M,K] f32/bf16; B: LB=0 [K,N] (legacy) / LB=1 [N,K].
// MODE: 0 plain,1 +bias,2 lrelu,3 sigmoid. OUTBF: bf16 C.
// ---------------------------------------------------------------------------
template<int MODE, bool AF32, bool BF32, int LB, bool OUTBF>
__global__ __launch_bounds__(256, 2) void mg(
    const void* __restrict__ Av, int lda,
    const void* __restrict__ Bv, int ldb,
    void* __restrict__ Cv, int ldc,
    int M, int N, int K, int Kreal,
    const float* __restrict__ bias)
{
  __shared__ u16 As[128 * 40];
  __shared__ u16 Bs[128 * 40];
  const int t = threadIdx.x;
  const int w = t >> 6, l = t & 63;
  const int l15 = l & 15, lhi = l >> 4;
  const int bm = blockIdx.y << 7, bn = blockIdx.x << 7;
  const int wm = (w >> 1) << 6, wn = (w & 1) << 6;
  const int srow = t >> 2, scol = (t & 3) << 3;
  const int bcol = t & 127, bkh = (t >> 7) << 4;

  f32x4 acc[4][4] = {};
  short8 pa[2], pb[2];

  auto LDA_ = [&](int kt) {
    #pragma unroll
    for (int c = 0; c < 2; ++c) {
      const int gc = kt + scol;
      short8 v = {};
      const int ga = bm + srow + (c << 6);
      if ((gc + 8 <= K) && ga < M) {
        if (AF32) {
          const float* p = (const float*)Av + (size_t)ga * lda + gc;
          #pragma unroll
          for (int j = 0; j < 8; ++j) v[j] = (short)f2bf(p[j]);
        } else {
          v = *(const short8*)((const u16*)Av + (size_t)ga * lda + gc);
        }
      }
      pa[c] = v;
    }
  };
  auto LDB_ = [&](int kt) {
    if (LB == 1) {
      #pragma unroll
      for (int c = 0; c < 2; ++c) {
        const int gc = kt + scol;
        short8 v = {};
        const int gn = bn + srow + (c << 6);
        if ((gc + 8 <= K) && gn < N) {
          if (BF32) {
            const float* p = (const float*)Bv + (size_t)gn * ldb + gc;
            #pragma unroll
            for (int j = 0; j < 8; ++j) v[j] = (short)f2bf(p[j]);
          } else {
            v = *(const short8*)((const u16*)Bv + (size_t)gn * ldb + gc);
          }
        }
        pb[c] = v;
      }
    } else {
      #pragma unroll
      for (int h = 0; h < 2; ++h) {
        const int k0 = bkh + (h << 3);
        short8 v = {};
        const int gn = bn + bcol;
        if (gn < N) {
          #pragma unroll
          for (int j = 0; j < 8; ++j) {
            const int gk = kt + k0 + j;
            if (gk < Kreal) {
              if (BF32) v[j] = (short)f2bf(((const float*)Bv)[(size_t)gk * ldb + gn]);
              else      v[j] = (short)((const u16*)Bv)[(size_t)gk * ldb + gn];
            }
          }
        }
        pb[h] = v;
      }
    }
  };

  LDA_(0); LDB_(0);
  for (int kt = 0; kt < K; kt += 32) {
    #pragma unroll
    for (int c = 0; c < 2; ++c)
      *(short8*)&As[(srow + (c << 6)) * 40 + scol] = pa[c];
    if (LB == 1) {
      #pragma unroll
      for (int c = 0; c < 2; ++c)
        *(short8*)&Bs[(srow + (c << 6)) * 40 + scol] = pb[c];
    } else {
      #pragma unroll
      for (int h = 0; h < 2; ++h)
        *(short8*)&Bs[bcol * 40 + bkh + (h << 3)] = pb[h];
    }
    __syncthreads();
    if (kt + 32 < K) { LDA_(kt + 32); LDB_(kt + 32); }
    short8 af[4], bfr[4];
    #pragma unroll
    for (int m = 0; m < 4; ++m)
      af[m] = *(const short8*)&As[(wm + (m << 4) + l15) * 40 + (lhi << 3)];
    #pragma unroll
    for (int n = 0; n < 4; ++n)
      bfr[n] = *(const short8*)&Bs[(wn + (n << 4) + l15) * 40 + (lhi << 3)];
    #pragma unroll
    for (int m = 0; m < 4; ++m) {
      #pragma unroll
      for (int n = 0; n < 4; ++n)
        acc[m][n] = __builtin_amdgcn_mfma_f32_16x16x32_bf16(
            __builtin_bit_cast(bf16x8, af[m]),
            __builtin_bit_cast(bf16x8, bfr[n]), acc[m][n], 0, 0, 0);
    }
    __syncthreads();
  }

  #pragma unroll
  for (int m = 0; m < 4; ++m) {
    #pragma unroll
    for (int n = 0; n < 4; ++n) {
      #pragma unroll
      for (int r = 0; r < 4; ++r) {
        const int row = bm + wm + (m << 4) + (lhi << 2) + r;
        const int col = bn + wn + (n << 4) + l15;
        if (row < M && col < N) {
          const float v0 = acc[m][n][r];
          float o;
          if (MODE == 0) o = v0;
          else if (MODE == 1) o = v0 + bias[col];
          else if (MODE == 2) { const float s = v0 + bias[col]; o = (s > 0.f) ? s : 0.2f * s; }
          else o = 1.f / (1.f + __expf(-v0));
          if (OUTBF) ((u16*)Cv)[(size_t)row * ldc + col] = f2bf(o);
          else       ((float*)Cv)[(size_t)row * ldc + col] = o;
        }
      }
    }
  }
}

// ---------------------------------------------------------------------------
// Split-K MFMA GEMM (narrow N<=128). B is ALWAYS bf16 B^T [N,K].
// Grid (1, M/128, KS); partials P[z][row][0..PN).
// ---------------------------------------------------------------------------
template<bool AF32>
__global__ __launch_bounds__(256, 2) void mgs(
    const void* __restrict__ Av, int lda,
    const u16* __restrict__ Bt, int ldb,
    float* __restrict__ P,
    int M, int N, int K, int KSZ, int PN)
{
  __shared__ u16 As[128 * 40];
  __shared__ u16 Bs[128 * 40];
  const int t = threadIdx.x;
  const int w = t >> 6, l = t & 63;
  const int l15 = l & 15, lhi = l >> 4;
  const int bm = blockIdx.y << 7;
  const int wm = (w >> 1) << 6, wn = (w & 1) << 6;
  const int srow = t >> 2, scol = (t & 3) << 3;
  const int kbeg = blockIdx.z * KSZ;
  const int kend = min(K, kbeg + KSZ);

  f32x4 acc[4][4] = {};
  short8 pa[2], pb[2];

  auto LDA_ = [&](int kt) {
    #pragma unroll
    for (int c = 0; c < 2; ++c) {
      const int gc = kt + scol;
      short8 v = {};
      const int ga = bm + srow + (c << 6);
      if ((gc + 8 <= K) && ga < M) {
        if (AF32) {
          const float* p = (const float*)Av + (size_t)ga * lda + gc;
          #pragma unroll
          for (int j = 0; j < 8; ++j) v[j] = (short)f2bf(p[j]);
        } else {
          v = *(const short8*)((const u16*)Av + (size_t)ga * lda + gc);
        }
      }
      pa[c] = v;
    }
  };
  auto LDB_ = [&](int kt) {
    #pragma unroll
    for (int c = 0; c < 2; ++c) {
      const int gc = kt + scol;
      short8 v = {};
      const int gn = srow + (c << 6);
      if ((gc + 8 <= K) && gn < N)
        v = *(const short8*)(Bt + (size_t)gn * ldb + gc);
      pb[c] = v;
    }
  };

  LDA_(kbeg); LDB_(kbeg);
  for (int kt = kbeg; kt < kend; kt += 32) {
    #pragma unroll
    for (int c = 0; c < 2; ++c)
      *(short8*)&As[(srow + (c << 6)) * 40 + scol] = pa[c];
    #pragma unroll
    for (int c = 0; c < 2; ++c)
      *(short8*)&Bs[(srow + (c << 6)) * 40 + scol] = pb[c];
    __syncthreads();
    if (kt + 32 < kend) { LDA_(kt + 32); LDB_(kt + 32); }
    short8 af[4], bfr[4];
    #pragma unroll
    for (int m = 0; m < 4; ++m)
      af[m] = *(const short8*)&As[(wm + (m << 4) + l15) * 40 + (lhi << 3)];
    #pragma unroll
    for (int n = 0; n < 4; ++n)
      bfr[n] = *(const short8*)&Bs[(wn + (n << 4) + l15) * 40 + (lhi << 3)];
    #pragma unroll
    for (int m = 0; m < 4; ++m) {
      #pragma unroll
      for (int n = 0; n < 4; ++n)
        acc[m][n] = __builtin_amdgcn_mfma_f32_16x16x32_bf16(
            __builtin_bit_cast(bf16x8, af[m]),
            __builtin_bit_cast(bf16x8, bfr[n]), acc[m][n], 0, 0, 0);
    }
    __syncthreads();
  }

  float* Pz = P + (size_t)blockIdx.z * M * PN;
  #pragma unroll
  for (int m = 0; m < 4; ++m) {
    #pragma unroll
    for (int n = 0; n < 4; ++n) {
      const int col = wn + (n << 4) + l15;
      if (col < PN) {
        #pragma unroll
        for (int r = 0; r < 4; ++r) {
          const int row = bm + wm + (m << 4) + (lhi << 2) + r;
          Pz[(size_t)row * PN + col] = acc[m][n][r];
        }
      }
    }
  }
}

template<int MODE, bool OUTBF>
__global__ void redk(const float* __restrict__ P, int KS, int PN,
                     void* __restrict__ Cv, int M, int N,
                     const float* __restrict__ bias)
{
  const int i = blockIdx.x * 256 + threadIdx.x;
  if (i >= M * N) return;
  const int row = i / N, col = i - row * N;
  float s = 0.f;
  for (int z = 0; z < KS; ++z) s += P[((size_t)z * M + row) * PN + col];
  float o;
  if (MODE == 0) o = s;
  else if (MODE == 1) o = s + bias[col];
  else { const float b = s + bias[col]; o = (b > 0.f) ? b : 0.2f * b; }
  if (OUTBF) ((u16*)Cv)[i] = f2bf(o);
  else       ((float*)Cv)[i] = o;
}

// Reduce split-K partials directly into TRANSPOSED bf16 B^T[N][M] (coalesced
// over M). Bit-identical to redk(OUTBF)+tr_k: same z-order sum, same f2bf.
// P reads are strided (PN*4 B) but P is L2-resident.
__global__ void redkT(const float* __restrict__ P, int KS, int PN,
                      u16* __restrict__ Bt, int M, int N)
{
  const long i = (long)blockIdx.x * 256 + threadIdx.x;
  if (i >= (long)M * N) return;
  const int n = (int)(i / M), m = (int)(i - (long)n * M);
  float s = 0.f;
  for (int z = 0; z < KS; ++z) s += P[((size_t)z * M + m) * PN + n];
  Bt[(size_t)n * M + m] = f2bf(s);
}

// ---------------------------------------------------------------------------
// Fused symmetric dual gram — EXACT r4 structure (best measured: 330us).
// r5 (2-deep prefetch), r6 (XCD swizzle), r7 (occupancy bound) all regressed
// — sharp local optimum; do not touch the K-loop.
// ---------------------------------------------------------------------------
template<bool TEST>
__global__ __launch_bounds__(256, 2) void gram2(
    const u16* __restrict__ Z1, int ld1, int K1,
    const u16* __restrict__ Z2, int ld2, int K2,
    float* __restrict__ C, int ldc, int M)
{
  __shared__ union SM {
    u16 stage[2][128 * 40];
    float tb[32][132];
  } sm;
  const int bx = blockIdx.x, by = blockIdx.y;
  if (bx < by) return;
  u16* As = sm.stage[0];
  u16* Bs = sm.stage[1];
  const int t = threadIdx.x;
  const int w = t >> 6, l = t & 63;
  const int l15 = l & 15, lhi = l >> 4;
  const int bm = by << 7, bn = bx << 7;
  const int wm = (w >> 1) << 6, wn = (w & 1) << 6;
  const int srow = t >> 2, scol = (t & 3) << 3;

  f32x4 acc1[4][4] = {};
  f32x4 acc2[4][4] = {};
  short8 va0, va1, vb0, vb1;

  auto LOD = [&](const u16* Z, int ld, int KK, int kt) {
    short8 a0 = {}, a1 = {}, b0 = {}, b1 = {};
    const int gc = kt + scol;
    if (gc + 8 <= KK) {
      a0 = *(const short8*)(Z + (size_t)(bm + srow) * ld + gc);
      a1 = *(const short8*)(Z + (size_t)(bm + srow + 64) * ld + gc);
      b0 = *(const short8*)(Z + (size_t)(bn + srow) * ld + gc);
      b1 = *(const short8*)(Z + (size_t)(bn + srow + 64) * ld + gc);
    }
    va0 = a0; va1 = a1; vb0 = b0; vb1 = b1;
  };
  auto STORE = [&]() {
    *(short8*)&As[srow * 40 + scol] = va0;
    *(short8*)&As[(srow + 64) * 40 + scol] = va1;
    *(short8*)&Bs[srow * 40 + scol] = vb0;
    *(short8*)&Bs[(srow + 64) * 40 + scol] = vb1;
  };
  auto FMM = [&](f32x4 (&ACC)[4][4]) {
    short8 af[4], bfr[4];
    #pragma unroll
    for (int m = 0; m < 4; ++m)
      af[m] = *(const short8*)&As[(wm + (m << 4) + l15) * 40 + (lhi << 3)];
    #pragma unroll
    for (int n = 0; n < 4; ++n)
      bfr[n] = *(const short8*)&Bs[(wn + (n << 4) + l15) * 40 + (lhi << 3)];
    #pragma unroll
    for (int m = 0; m < 4; ++m) {
      #pragma unroll
      for (int n = 0; n < 4; ++n)
        ACC[m][n] = __builtin_amdgcn_mfma_f32_16x16x32_bf16(
            __builtin_bit_cast(bf16x8, af[m]),
            __builtin_bit_cast(bf16x8, bfr[n]), ACC[m][n], 0, 0, 0);
    }
  };

  LOD(Z1, ld1, K1, 0);
  for (int kt = 0; kt < K1; kt += 32) {
    STORE();
    __syncthreads();
    if (kt + 32 < K1) LOD(Z1, ld1, K1, kt + 32);
    else LOD(Z2, ld2, K2, 0);
    FMM(acc1);
    __syncthreads();
  }
  for (int kt = 0; kt < K2; kt += 32) {
    STORE();
    __syncthreads();
    if (kt + 32 < K2) LOD(Z2, ld2, K2, kt + 32);
    FMM(acc2);
    __syncthreads();
  }

  auto cval = [&](int m, int n, int r) -> float {
    const float a1 = acc1[m][n][r], a2 = acc2[m][n][r];
    if (TEST) return a1 + a2;
    return 1.f / (1.f + __expf(-a1)) + 1.f / (1.f + __expf(-a2));
  };

  #pragma unroll
  for (int m = 0; m < 4; ++m) {
    #pragma unroll
    for (int n = 0; n < 4; ++n) {
      #pragma unroll
      for (int r = 0; r < 4; ++r) {
        const int row = bm + wm + (m << 4) + (lhi << 2) + r;
        const int col = bn + wn + (n << 4) + l15;
        C[(size_t)row * ldc + col] = cval(m, n, r);
      }
    }
  }

  if (bx != by) {
    #pragma unroll
    for (int p = 0; p < 4; ++p) {
      __syncthreads();
      if (wn == ((p & 2) << 5)) {
        #pragma unroll
        for (int n2 = 0; n2 < 2; ++n2) {
          const int n = ((p & 1) << 1) + n2;
          #pragma unroll
          for (int m = 0; m < 4; ++m)
            #pragma unroll
            for (int r = 0; r < 4; ++r)
              sm.tb[(n2 << 4) + l15][wm + (m << 4) + (lhi << 2) + r] = cval(m, n, r);
        }
      }
      __syncthreads();
      #pragma unroll
      for (int i = 0; i < 16; ++i) {
        const int e = t + (i << 8);
        const int rr = e >> 7, cc = e & 127;
        C[(size_t)(bn + (p << 5) + rr) * ldc + bm + cc] = sm.tb[rr][cc];
      }
    }
  }
}

// --------------------------- small kernels ---------------------------------
__global__ void zi_k(const float* __restrict__ a, const float* __restrict__ zae,
                     const float* __restrict__ zsg, u16* __restrict__ zi)
{
  const int i = blockIdx.x * 256 + threadIdx.x;
  if (i < 163840) {
    const float av = a[i];
    zi[i] = f2bf(av * zae[i] + (1.f - av) * zsg[i]);
  }
}

__global__ void f2bf4_k(const float* __restrict__ s, u16* __restrict__ d, long n4)
{
  long i = (long)blockIdx.x * 256 + threadIdx.x;
  const long stride = (long)gridDim.x * 256;
  for (; i < n4; i += stride) {
    const float4 v = ((const float4*)s)[i];
    union { u16 h[4]; unsigned long long u; } o;
    o.h[0] = f2bf(v.x); o.h[1] = f2bf(v.y); o.h[2] = f2bf(v.z); o.h[3] = f2bf(v.w);
    ((unsigned long long*)d)[i] = o.u;
  }
}

// 8192 x 2000 f32 -> 8192 x 2016 bf16, zero pad cols [2000,2016).
__global__ void padzhb_k(const float* __restrict__ s, u16* __restrict__ d)
{
  const int row = blockIdx.x;
  for (int g = threadIdx.x; g < 504; g += 256) {
    const int c4 = g << 2;
    union { u16 h[4]; unsigned long long u; } o;
    if (c4 < 2000) {
      const float4 v = *(const float4*)(s + (size_t)row * 2000 + c4);
      o.h[0] = f2bf(v.x); o.h[1] = f2bf(v.y); o.h[2] = f2bf(v.z); o.h[3] = f2bf(v.w);
    } else {
      o.u = 0ULL;
    }
    *(unsigned long long*)(d + (size_t)row * 2016 + c4) = o.u;
  }
}

__global__ void padbf_k(const float* __restrict__ s, u16* __restrict__ d)
{
  const int i = blockIdx.x * 256 + threadIdx.x;
  const int row = i >> 5, col = i & 31;
  d[i] = (col < 20) ? f2bf(s[row * 20 + col]) : (u16)0;
}

__global__ __launch_bounds__(256) void attn_f(const float* __restrict__ zl,
                                              const float* __restrict__ gammap,
                                              u16* __restrict__ ztp,
                                              float* __restrict__ ztout)
{
  __shared__ float tile[256 * 20];
  const int t = threadIdx.x;
  const int sub = t & 31;
  const int row = blockIdx.x * 8 + (t >> 5);
  float qv[20];
  #pragma unroll
  for (int k = 0; k < 20; ++k) qv[k] = zl[(size_t)row * 20 + k];
  float m = -1e30f, ssum = 0.f;
  float acc[20] = {};
  for (int j0 = 0; j0 < 8192; j0 += 256) {
    #pragma unroll
    for (int k = 0; k < 20; ++k) tile[t * 20 + k] = zl[(size_t)(j0 + t) * 20 + k];
    __syncthreads();
    for (int jj = 0; jj < 8; ++jj) {
      const int jl = (jj << 5) + sub;
      float s = 0.f;
      #pragma unroll
      for (int k = 0; k < 20; ++k) s += qv[k] * tile[jl * 20 + k];
      if (s > m) {
        const float sc = __expf(m - s);
        ssum *= sc;
        #pragma unroll
        for (int k = 0; k < 20; ++k) acc[k] *= sc;
        m = s;
      }
      const float p = __expf(s - m);
      ssum += p;
      #pragma unroll
      for (int k = 0; k < 20; ++k) acc[k] += p * tile[jl * 20 + k];
    }
    __syncthreads();
  }
  #pragma unroll
  for (int off = 16; off >= 1; off >>= 1) {
    const float mo = __shfl_xor(m, off, 32);
    const float so = __shfl_xor(ssum, off, 32);
    const float nm = fmaxf(m, mo);
    const float e1 = __expf(m - nm), e2 = __expf(mo - nm);
    ssum = ssum * e1 + so * e2;
    #pragma unroll
    for (int k = 0; k < 20; ++k) {
      const float ao = __shfl_xor(acc[k], off, 32);
      acc[k] = acc[k] * e1 + ao * e2;
    }
    m = nm;
  }
  if (sub == 0) {
    const float g = gammap[0];
    #pragma unroll
    for (int k = 0; k < 20; ++k) {
      const float v = g * (acc[k] / ssum) + qv[k];
      ztout[(size_t)row * 20 + k] = v;
      ztp[(size_t)row * 32 + k] = f2bf(v);
    }
    #pragma unroll
    for (int k = 20; k < 32; ++k) ztp[(size_t)row * 32 + k] = 0;
  }
}

template<bool BFIN>
__global__ void softassign_k(const void* __restrict__ zp, int stride,
                             const float* __restrict__ cl, float* __restrict__ outq)
{
  const int i = blockIdx.x * 256 + threadIdx.x;
  float zv[20];
  #pragma unroll
  for (int k = 0; k < 20; ++k)
    zv[k] = BFIN ? bf2f(((const u16*)zp)[(size_t)i * stride + k])
                 : ((const float*)zp)[(size_t)i * stride + k];
  float qv[10], s = 0.f;
  #pragma unroll
  for (int j = 0; j < 10; ++j) {
    float d2 = 0.f;
    #pragma unroll
    for (int k = 0; k < 20; ++k) { const float d = zv[k] - cl[j * 20 + k]; d2 += d * d; }
    qv[j] = 1.f / (1.f + d2);
    s += qv[j];
  }
  const float inv = 1.f / s;
  #pragma unroll
  for (int j = 0; j < 10; ++j) outq[(size_t)i * 10 + j] = qv[j] * inv;
}

// --------------------------- self-test -------------------------------------
DEV float stA(int i, int k) { return (float)(((i * 5 + k * 7) % 3) - 1); }
DEV float stB(int j, int k) { return (float)(((j * 11 + k * 13) % 5) - 2); }

__global__ void st_setup(u16* At, float* Atf, u16* Bnk, float* Bknf, u16* Bknb, int* fl)
{
  const int idx = blockIdx.x * 256 + threadIdx.x;
  { const int i = idx >> 6, k = idx & 63;
    At[idx] = f2bf(stA(i, k)); Atf[idx] = stA(i, k);
    Bnk[idx] = f2bf(stB(i, k)); }
  { const int k = idx >> 7, j = idx & 127;
    Bknf[idx] = stB(j, k); Bknb[idx] = f2bf(stB(j, k)); }
  if (idx == 0) *fl = 0;
}

__global__ void st_check(const float* C, int bit, int* fl)
{
  const int i = blockIdx.x, j = threadIdx.x;
  float ref = 0.f;
  for (int k = 0; k < 64; ++k) ref += stA(i, k) * stB(j, k);
  if (C[i * 128 + j] != ref) atomicOr(fl, bit);
}

// transposed bf16 check (values are small integers, bf16-exact)
__global__ void st_checkT(const u16* Ct, int* fl)
{
  const int i = blockIdx.x, j = threadIdx.x;
  float ref = 0.f;
  for (int k = 0; k < 64; ++k) ref += stA(i, k) * stB(j, k);
  if (bf2f(Ct[j * 128 + i]) != ref) atomicOr(fl, 32);
}

__global__ void st2_setup(u16* Z1, u16* Z2)
{
  const int idx = blockIdx.x * 256 + threadIdx.x;
  if (idx < 8192)  { const int i = idx >> 5, k = idx & 31; Z1[idx] = f2bf(stA(i, k)); }
  if (idx < 16384) { const int i = idx >> 6, k = idx & 63; Z2[idx] = f2bf(stB(i, k)); }
}

__global__ void st2_check(const float* C, int* fl)
{
  const int i = blockIdx.x, j = threadIdx.x;
  float ref = 0.f;
  for (int k = 0; k < 32; ++k) ref += stA(i, k) * stA(j, k);
  for (int k = 0; k < 64; ++k) ref += stB(i, k) * stB(j, k);
  if (C[i * 256 + j] != ref) atomicOr(fl, 16);
}

__global__ void st_probe(float* out0, const int* fl)
{
  if (threadIdx.x == 0 && blockIdx.x == 0 && *fl) *out0 = 4096.f + (float)(*fl);
}

// ---------------------------------------------------------------------------
extern "C" void kernel_launch(void* const* d_in, const int* in_sizes, int n_in,
                              void* d_out, int out_size, void* d_ws, size_t ws_size,
                              hipStream_t stream)
{
  (void)in_sizes; (void)n_in; (void)out_size;
  const float* x     = (const float*)d_in[0];
  const float* adj   = (const float*)d_in[1];
  const float* a     = (const float*)d_in[2];
  const float* cl    = (const float*)d_in[3];
  const float* gamma = (const float*)d_in[4];
  const float* We1 = (const float*)d_in[5];  const float* be1 = (const float*)d_in[6];
  const float* We2 = (const float*)d_in[7];  const float* be2 = (const float*)d_in[8];
  const float* We3 = (const float*)d_in[9];  const float* be3 = (const float*)d_in[10];
  const float* Wz  = (const float*)d_in[11]; const float* bz  = (const float*)d_in[12];
  const float* Wd1 = (const float*)d_in[13]; const float* bd1 = (const float*)d_in[14];
  const float* Wd2 = (const float*)d_in[15]; const float* bd2 = (const float*)d_in[16];
  const float* Wd3 = (const float*)d_in[17]; const float* bd3 = (const float*)d_in[18];
  const float* Wx  = (const float*)d_in[19]; const float* bx  = (const float*)d_in[20];
  const float* Wg1 = (const float*)d_in[21];
  const float* Wg2 = (const float*)d_in[22];
  const float* Wg3 = (const float*)d_in[23];
  const float* Wg4 = (const float*)d_in[24];
  const float* Wg5 = (const float*)d_in[25];
  const float* Wg6 = (const float*)d_in[26];
  float* out = (float*)d_out;

  const size_t OFF_XHAT = 0;
  const size_t OFF_ZHAT = 16384000;
  const size_t OFF_ADJ  = 32768000;
  const size_t OFF_ZAE  = 99876864;
  const size_t OFF_ZSG  = 100040704;
  const size_t OFF_Q    = 100204544;
  const size_t OFF_Q1   = 100286464;
  const size_t OFF_Q2   = 100368384;
  const size_t OFF_ZT   = 100450304;

  char* cur = (char*)d_ws;
  auto ab = [&](size_t bytes) {
    char* p = cur;
    cur += ((bytes + 255) & ~(size_t)255);
    return p;
  };
  u16*  h1   = (u16*)ab(8192 * 128 * 2);
  u16*  h2   = (u16*)ab(8192 * 256 * 2);
  u16*  h3   = (u16*)ab(8192 * 512 * 2);
  u16*  tA   = (u16*)ab(8192 * 128 * 2);
  u16*  tC   = (u16*)ab(8192 * 256 * 2);
  u16*  t3T  = (u16*)ab(20 * 8192 * 2);    // transposed chain buffers
  u16*  tBT  = (u16*)ab(20 * 8192 * 2);
  u16*  aztpT = (u16*)ab(32 * 8192 * 2);
  u16*  avT   = (u16*)ab(32 * 8192 * 2);
  u16*  zsgb = (u16*)ab(8192 * 32 * 2);
  u16*  zib  = (u16*)ab(8192 * 20 * 2);
  float* zl  = (float*)ab(8192 * 20 * 4);
  u16*  ztp  = (u16*)ab(8192 * 32 * 2);
  u16*  aztp = (u16*)ab(8192 * 32 * 2);
  float* W45 = (float*)ab(20 * 128 * 4);
  u16*  zhb  = (u16*)ab((size_t)8192 * 2016 * 2);
  u16*  xb   = (u16*)ab((size_t)8192 * 2000 * 2);
  // transposed-B operands (bf16 [N,K])
  u16*  trB  = (u16*)ab((size_t)128 * 8192 * 2);   // reused: zib^T, ztp^T, Wg5t
  u16*  We1t = (u16*)ab(128 * 2016 * 2);
  u16*  We2t = (u16*)ab(256 * 128 * 2);
  u16*  We3t = (u16*)ab(512 * 256 * 2);
  u16*  Wzt  = (u16*)ab(32 * 512 * 2);
  u16*  Wd1t = (u16*)ab(512 * 32 * 2);
  u16*  Wd2t = (u16*)ab(256 * 512 * 2);
  u16*  Wd3t = (u16*)ab(128 * 256 * 2);
  u16*  Wxt  = (u16*)ab(2000 * 128 * 2);
  u16*  Wg2t = (u16*)ab(256 * 128 * 2);
  u16*  Wg3t = (u16*)ab(32 * 256 * 2);
  u16*  Wg6t = (u16*)ab(2000 * 128 * 2);
  u16*  W123t = (u16*)ab(32 * 2016 * 2);   // (Wg1@Wg2@Wg3)^T, K zero-padded
  u16*  W456t = (u16*)ab(2000 * 32 * 2);   // (W45@Wg6)^T,    K zero-padded
  u16*  sAt  = (u16*)ab(8192 * 2);
  float* sAtf = (float*)ab(8192 * 4);
  u16*  sBnk = (u16*)ab(8192 * 2);
  float* sBknf = (float*)ab(8192 * 4);
  u16*  sBknb = (u16*)ab(8192 * 2);
  u16*  sBt32 = (u16*)ab(128 * 64 * 2);
  u16*  sBtb  = (u16*)ab(128 * 64 * 2);
  float* sCt = (float*)ab(128 * 128 * 4);
  u16*  sCtT = (u16*)ab(128 * 128 * 2);
  u16*  sZ1  = (u16*)ab(256 * 32 * 2);
  u16*  sZ2  = (u16*)ab(256 * 64 * 2);
  float* sCt2 = (float*)ab(256 * 256 * 4);
  int*  sfl  = (int*)ab(256);

  // outputs double as f32 intermediates (values written once, final)
  float* zae = out + OFF_ZAE;
  float* zsg = out + OFF_ZSG;

  const size_t fixedB = (size_t)(cur - (char*)d_ws);
  const size_t P16B = (size_t)16 * 8192 * 128 * 4;
  const size_t P8B  = (size_t)8 * 8192 * 128 * 4;
  const size_t ADJB = (size_t)8192 * 8192 * 2;
  const bool kbig = (fixedB + P16B + ADJB) <= ws_size;
  float* P = (float*)ab(kbig ? P16B : P8B);
  u16* adjb = (u16*)cur;
  const bool use_adjb = ((size_t)(cur - (char*)d_ws) + ADJB) <= ws_size;
  // KS=8 everywhere (r8 win): halves split-K partial traffic at identical
  // residency (512 blocks = 2/CU exactly).
  const int KS_ADJ = 8;
  const int KSZ_ADJ = 1024;
  const int KS_2K = 8;
  const int KSZ_2K = 256;

  #define GD(N, M) dim3(((N) + 127) / 128, ((M) + 127) / 128)
  #define MG(MODE, AF, BF, LB, OB, A, LDA, B, LDB, C, LDC, M, N, K, KR, BIAS) \
    mg<MODE, AF, BF, LB, OB><<<GD(N, M), 256, 0, stream>>>( \
        A, LDA, B, LDB, C, LDC, M, N, K, KR, BIAS)
  #define MGS(RMODE, AF, OB, A, LDA, BT, LDB, C, M, N, K, KS, KSZ, PN, BIAS) do { \
    mgs<AF><<<dim3(1, (M) / 128, KS), 256, 0, stream>>>( \
        A, LDA, BT, LDB, P, M, N, K, KSZ, PN); \
    redk<RMODE, OB><<<(((M) * (N)) + 255) / 256, 256, 0, stream>>>( \
        P, KS, PN, C, M, N, BIAS); \
  } while (0)
  // split-K GEMM with TRANSPOSED bf16 output (for chained adj-multiplies)
  #define MGST(AF, A, LDA, BT, LDB, CT, M, N, K, KS, KSZ, PN) do { \
    mgs<AF><<<dim3(1, (M) / 128, KS), 256, 0, stream>>>( \
        A, LDA, BT, LDB, P, M, N, K, KSZ, PN); \
    redkT<<<(((M) * (N)) + 255) / 256, 256, 0, stream>>>( \
        P, KS, PN, CT, M, N); \
  } while (0)
  #define TR32(S, R, C, LD, D, LDD, KP) \
    tr_k<true><<<dim3(((KP) + 63) / 64, ((C) + 63) / 64), 256, 0, stream>>>( \
        S, R, C, LD, D, LDD, KP)
  #define TRB(S, R, C, LD, D, LDD, KP) \
    tr_k<false><<<dim3(((KP) + 63) / 64, ((C) + 63) / 64), 256, 0, stream>>>( \
        S, R, C, LD, D, LDD, KP)
  // adj multiply, input B^T, output B^T (stays in transposed layout)
  #define ADJT(BTIN, CTOUT, N) do { \
    if (use_adjb) MGST(false, adjb, 8192, BTIN, 8192, CTOUT, 8192, N, 8192, KS_ADJ, KSZ_ADJ, 32); \
    else          MGST(true,  adj,  8192, BTIN, 8192, CTOUT, 8192, N, 8192, KS_ADJ, KSZ_ADJ, 32); \
  } while (0)
  // adj multiply, input B^T, output row-major (f32 or bf16)
  #define ADJR(BTIN, C, N, OB) do { \
    if (use_adjb) MGS(0, false, OB, adjb, 8192, BTIN, 8192, C, 8192, N, 8192, KS_ADJ, KSZ_ADJ, 32, nullptr); \
    else          MGS(0, true,  OB, adj,  8192, BTIN, 8192, C, 8192, N, 8192, KS_ADJ, KSZ_ADJ, 32, nullptr); \
  } while (0)

  // --- self-tests (exact integer arithmetic; sentinel on failure) ---
  st_setup<<<32, 256, 0, stream>>>(sAt, sAtf, sBnk, sBknf, sBknb, sfl);
  MG(0, false, false, 1, false, sAt, 64, sBnk, 64, sCt, 128, 128, 128, 64, 64, nullptr);
  st_check<<<128, 128, 0, stream>>>(sCt, 1, sfl);
  TR32(sBknf, 64, 128, 128, sBt32, 64, 64);
  MG(0, true, false, 1, false, sAtf, 64, sBt32, 64, sCt, 128, 128, 128, 64, 64, nullptr);
  st_check<<<128, 128, 0, stream>>>(sCt, 2, sfl);
  TRB(sBknb, 64, 128, 128, sBtb, 64, 64);
  MGS(0, false, false, sAt, 64, sBtb, 64, sCt, 128, 128, 64, 2, 32, 128, nullptr);
  st_check<<<128, 128, 0, stream>>>(sCt, 8, sfl);
  // redkT path: re-reduce the SAME partials transposed, check C^T (bit 32)
  redkT<<<(128 * 128 + 255) / 256, 256, 0, stream>>>(P, 2, 128, sCtT, 128, 128);
  st_checkT<<<128, 128, 0, stream>>>(sCtT, sfl);
  st2_setup<<<64, 256, 0, stream>>>(sZ1, sZ2);
  gram2<true><<<dim3(2, 2), 256, 0, stream>>>(sZ1, 32, 32, sZ2, 64, 64, sCt2, 256, 256);
  st2_check<<<256, 256, 0, stream>>>(sCt2, sfl);

  // --- one-time weight transposes (f32 [K,N] -> bf16 [N,Kpad]) ---
  TR32(We1, 2000, 128, 128, We1t, 2016, 2016);
  TR32(We2, 128, 256, 256, We2t, 128, 128);
  TR32(We3, 256, 512, 512, We3t, 256, 256);
  TR32(Wz,  512, 20,  20,  Wzt,  512, 512);
  TR32(Wd1, 20,  512, 512, Wd1t, 32,  32);
  TR32(Wd2, 512, 256, 256, Wd2t, 512, 512);
  TR32(Wd3, 256, 128, 128, Wd3t, 256, 256);
  TR32(Wx,  128, 2000, 2000, Wxt, 128, 128);
  TR32(Wg2, 128, 256, 256, Wg2t, 128, 128);
  TR32(Wg3, 256, 20,  20,  Wg3t, 256, 256);
  TR32(Wg6, 128, 2000, 2000, Wg6t, 128, 128);

  if (use_adjb)
    f2bf4_k<<<2048, 256, 0, stream>>>(adj, adjb, 16777216L);
  f2bf4_k<<<2048, 256, 0, stream>>>(x, xb, 4096000L);

  // --- AE encoder ---
  MGS(2, false, true, xb, 2000, We1t, 2016, h1, 8192, 128, 2000, KS_2K, KSZ_2K, 128, be1);
  MG(2, false, false, 1, true, h1, 128,  We2t, 128, h2, 256, 8192, 256, 128, 128, be2);
  MG(2, false, false, 1, true, h2, 256,  We3t, 256, h3, 512, 8192, 512, 256, 256, be3);
  MGS(1, false, false, h3, 512, Wzt, 512, zae, 8192, 20, 512, 4, 128, 32, bz);  // -> out

  // --- SGAE encoder (reassociated, transposed chain):
  //     zsg = adj@adj@adj@(x@W123), W123 = Wg1@Wg2@Wg3 [2000,20] ---
  MG(0, true, false, 1, true, Wg1, 128, Wg2t, 128, tC, 256, 2000, 256, 128, 128, nullptr);
  MG(0, false, false, 1, true, tC, 256, Wg3t, 256, tA, 20, 2000, 20, 256, 256, nullptr);
  TRB(tA, 2000, 20, 20, W123t, 2016, 2016);
  MGST(false, xb, 2000, W123t, 2016, t3T, 8192, 20, 2000, KS_2K, KSZ_2K, 32);  // (x@W123)^T
  ADJT(t3T, tBT, 20);                 // (adj @ .)^T
  ADJT(tBT, t3T, 20);                 // (adj @ .)^T
  ADJR(t3T, zsg, 20, false);          // zsg f32 -> out
  padbf_k<<<1024, 256, 0, stream>>>(zsg, zsgb);

  // --- fuse + attention ---
  zi_k<<<640, 256, 0, stream>>>(a, zae, zsg, zib);
  TRB(zib, 8192, 20, 20, trB, 8192, 8192);
  ADJR(trB, zl, 20, false);           // zl f32
  attn_f<<<1024, 256, 0, stream>>>(zl, gamma, ztp, out + OFF_ZT);

  // --- AE decoder ---
  u16* d1 = h3; u16* d2 = h2; u16* d3 = h1;
  MG(2, false, false, 1, true, ztp, 32, Wd1t, 32, d1, 512, 8192, 512, 32, 32, bd1);
  MG(2, false, false, 1, true, d1, 512, Wd2t, 512, d2, 256, 8192, 256, 512, 512, bd2);
  MGS(2, false, true, d2, 256, Wd3t, 256, d3, 8192, 128, 256, 4, 64, 128, bd3);
  MG(1, false, false, 1, false, d3, 128, Wxt, 128, out + OFF_XHAT, 2000,
     8192, 2000, 128, 128, bx);

  // --- SGAE decoder (reassociated, transposed chain):
  //     z_hat = (adj@adj@adj@zt)@(Wg4@Wg5@Wg6) ---
  TRB(ztp, 8192, 32, 32, trB, 8192, 8192);
  ADJT(trB, aztpT, 32);               // (adj @ zt)^T
  u16* Wg5t = trB;   // trB free after the mgs above (stream-ordered)
  TR32(Wg5, 256, 128, 128, Wg5t, 256, 256);
  MG(0, true, false, 1, false, Wg4, 256, Wg5t, 256, W45, 128, 20, 128, 256, 256, nullptr);
  MG(0, true, false, 1, true, W45, 128, Wg6t, 128, tC, 2000, 20, 2000, 128, 128, nullptr);
  TRB(tC, 20, 2000, 2000, W456t, 32, 32);
  ADJT(aztpT, avT, 32);               // (adj @ .)^T
  ADJR(avT, aztp, 32, true);          // row-major bf16 [8192][32]
  MG(0, false, false, 1, false, aztp, 32, W456t, 32, out + OFF_ZHAT, 2000,
     8192, 2000, 32, 32, nullptr);
  padzhb_k<<<8192, 256, 0, stream>>>(out + OFF_ZHAT, zhb);

  // --- adj_hat = sigmoid(zsg gram) + sigmoid(zhat gram), fused symmetric ---
  gram2<false><<<dim3(64, 64), 256, 0, stream>>>(zsgb, 32, 32, zhb, 2016, 2016,
                                                 out + OFF_ADJ, 8192, 8192);

  // --- soft assignments ---
  softassign_k<true><<<32, 256, 0, stream>>>(ztp, 32, cl, out + OFF_Q);
  softassign_k<false><<<32, 256, 0, stream>>>(zae, 20, cl, out + OFF_Q1);
  softassign_k<false><<<32, 256, 0, stream>>>(zsg, 20, cl, out + OFF_Q2);

  st_probe<<<1, 64, 0, stream>>>(out, sfl);

  #undef GD
  #undef MG
  #undef MGS
  #undef MGST
  #undef ADJT
  #undef ADJR
  #undef TR32
  #undef TRB
}